// Round 11
// baseline (660.729 us; speedup 1.0000x reference)
//
#include <hip/hip_runtime.h>
#include <hip/hip_bf16.h>
#include <stdint.h>

#define DDIM 256
#define NSHARD 8          // shards for deg_out atomics
#define T1 4096           // edges per bin1 block
#define NCPAD 128         // padded coarse-bin count (dst>>9, 512 rows/bin)
#define CCAP 9216         // record capacity per (rel, coarse bin); mean 8192, +11 sigma
#define NSLICE 8          // column slices (64 B each): 3.2 MB working set per slice

typedef short s8v __attribute__((ext_vector_type(8)));
typedef float f4v __attribute__((ext_vector_type(4)));

__device__ __forceinline__ float bf2f(unsigned u) { return __uint_as_float(u << 16); }
__device__ __forceinline__ unsigned short f2bf(float f) {
    __hip_bfloat16 h = __float2bfloat16(f);
    return *reinterpret_cast<unsigned short*>(&h);
}
__device__ __forceinline__ unsigned pack2(float a, float b) {
    return (unsigned)f2bf(a) | ((unsigned)f2bf(b) << 16);
}

// ---------------- fused W transpose + cast: T[n][k] = bf16(W[k][n]) ----------------
__global__ void transpose3_k(const float* __restrict__ W0, const float* __restrict__ W1,
                             const float* __restrict__ W2, __hip_bfloat16* __restrict__ T0,
                             __hip_bfloat16* __restrict__ T1v, __hip_bfloat16* __restrict__ T2) {
    const float* W = (blockIdx.y == 0) ? W0 : (blockIdx.y == 1) ? W1 : W2;
    __hip_bfloat16* T = (blockIdx.y == 0) ? T0 : (blockIdx.y == 1) ? T1v : T2;
    T[blockIdx.x * DDIM + threadIdx.x] = __float2bfloat16(W[threadIdx.x * DDIM + blockIdx.x]);
}

// ---------------- pass 1: LDS-staged coarse binning (dense segment writes) ----------------
// record = src | (dst&511)<<16 | bin<<25 ; bin = dst>>9.
__global__ __launch_bounds__(256) void bin1_k(
    const int* __restrict__ s0, const int* __restrict__ d0,
    const int* __restrict__ s1, const int* __restrict__ d1,
    const int* __restrict__ s2, const int* __restrict__ d2,
    int* __restrict__ cs_shard,      // [NSHARD][3N]
    int* __restrict__ gcur,          // [3][NCPAD]
    unsigned* __restrict__ recs,     // [3][NCPAD][CCAP]
    int N, int E) {
    __shared__ unsigned stage[T1];           // 16 KB
    __shared__ int hcnt[NCPAD], hoff[NCPAD], lbase[NCPAD], lcur[NCPAD];
    const int t = threadIdx.x;
    const int rel = blockIdx.y;
    const int* s = (rel == 0) ? s0 : (rel == 1) ? s1 : s2;
    const int* d = (rel == 0) ? d0 : (rel == 1) ? d1 : d2;
    const int e0 = blockIdx.x * T1;
    const int n = min(T1, E - e0);
    int* csb = cs_shard + ((size_t)(blockIdx.x & (NSHARD - 1)) * 3 + rel) * N;

    if (t < NCPAD) { hcnt[t] = 0; lcur[t] = 0; }
    __syncthreads();

    int ssr[T1 / 256], ddr[T1 / 256];
    #pragma unroll
    for (int k = 0; k < T1 / 256; ++k) {
        const int li = k * 256 + t;
        const bool v = li < n;
        ssr[k] = v ? s[e0 + li] : -1;
        ddr[k] = v ? d[e0 + li] : -1;
        if (v) {
            atomicAdd(&hcnt[ddr[k] >> 9], 1);
            atomicAdd(&csb[ssr[k]], 1);
        }
    }
    __syncthreads();

    if (t < 64) {
        const int a0 = hcnt[2 * t], a1 = hcnt[2 * t + 1];
        const int sum = a0 + a1;
        int incl = sum;
        #pragma unroll
        for (int off = 1; off < 64; off <<= 1) {
            const int u = __shfl_up(incl, off);
            if (t >= off) incl += u;
        }
        const int excl = incl - sum;
        hoff[2 * t] = excl;
        hoff[2 * t + 1] = excl + a0;
    }
    __syncthreads();
    if (t < NCPAD) lbase[t] = atomicAdd(&gcur[rel * NCPAD + t], hcnt[t]);
    __syncthreads();

    #pragma unroll
    for (int k = 0; k < T1 / 256; ++k) {
        if (ddr[k] >= 0) {
            const int b = ddr[k] >> 9;
            const int p = atomicAdd(&lcur[b], 1);
            stage[hoff[b] + p] = (unsigned)ssr[k] | ((unsigned)(ddr[k] & 511) << 16)
                                 | ((unsigned)b << 25);
        }
    }
    __syncthreads();

    for (int i = t; i < n; i += 256) {
        const unsigned r = stage[i];
        const int b = (int)(r >> 25);
        const int pos = lbase[b] + (i - hoff[b]);
        if (pos < CCAP)
            recs[((size_t)rel * NCPAD + b) * CCAP + pos] = r & 0x1FFFFFFu;
    }
}

// ---------------- fold sharded deg_out ----------------
__global__ void reduce_cs_k(const int* __restrict__ cs_shard, int* __restrict__ cs, int n3) {
    const int i = blockIdx.x * blockDim.x + threadIdx.x;
    if (i >= n3) return;
    int v = 0;
    #pragma unroll
    for (int s = 0; s < NSHARD; ++s) v += cs_shard[(size_t)s * n3 + i];
    cs[i] = v;
}

// ---------------- pass 2: per-coarse-bin LDS counting sort by dst row ----------------
__global__ __launch_bounds__(256) void sort_k(
    unsigned* __restrict__ recs, const int* __restrict__ gcur,
    int* __restrict__ row_beg, int* __restrict__ row_cnt, int N, int ncb) {
    __shared__ unsigned stage[CCAP];     // 36 KB
    __shared__ int rc[512], ro[512], rcur[512];
    const int t = threadIdx.x;
    const int rel = blockIdx.x / ncb, bin = blockIdx.x % ncb;
    const size_t base = ((size_t)rel * NCPAD + bin) * CCAP;
    const int n = min(gcur[rel * NCPAD + bin], CCAP);

    for (int i = t; i < 512; i += 256) rc[i] = 0;
    __syncthreads();
    for (int i = t; i < n; i += 256) {
        const unsigned r = recs[base + i];
        stage[i] = r;
        atomicAdd(&rc[(r >> 16) & 511], 1);
    }
    __syncthreads();
    if (t < 64) {
        int v[8], p[8], sum = 0;
        #pragma unroll
        for (int j = 0; j < 8; ++j) { v[j] = rc[t * 8 + j]; p[j] = sum; sum += v[j]; }
        int incl = sum;
        #pragma unroll
        for (int off = 1; off < 64; off <<= 1) {
            const int u = __shfl_up(incl, off);
            if (t >= off) incl += u;
        }
        const int excl = incl - sum;
        #pragma unroll
        for (int j = 0; j < 8; ++j) { ro[t * 8 + j] = excl + p[j]; rcur[t * 8 + j] = excl + p[j]; }
    }
    __syncthreads();
    for (int i = t; i < 512; i += 256) {
        const int grow = bin * 512 + i;
        if (grow < N) {
            row_cnt[(size_t)rel * N + grow] = rc[i];
            row_beg[(size_t)rel * N + grow] = (int)(base + ro[i]);
        }
    }
    for (int i = t; i < n; i += 256) {
        const unsigned r = stage[i];
        const int pos = atomicAdd(&rcur[(r >> 16) & 511], 1);
        recs[base + pos] = r & 0xffffu;
    }
}

// ---------------- dual-output GEMM: Y0 = bf16(s0(X@W0)), Y1 = bf16(s1(X@W1)) ----------------
__global__ __launch_bounds__(256, 2) void gemm2_k(
    const float* __restrict__ X,
    const __hip_bfloat16* __restrict__ Wt0, const __hip_bfloat16* __restrict__ Wt1,
    const int* __restrict__ deg0, const int* __restrict__ deg1,
    __hip_bfloat16* __restrict__ Y0, __hip_bfloat16* __restrict__ Y1, int M) {
    const int lane = threadIdx.x & 63, wid = threadIdx.x >> 6;
    const int c = lane & 15, kb = lane >> 4;
    const int rA = blockIdx.x * 128 + wid * 32 + c;
    const int rB = rA + 16;
    const bool vA = rA < M, vB = rB < M;
    const int rAc = vA ? rA : (M - 1), rBc = vB ? rB : (M - 1);

    s8v xfA[8], xfB[8];
    const float* xA = X + (size_t)rAc * DDIM;
    const float* xB = X + (size_t)rBc * DDIM;
    #pragma unroll
    for (int ks = 0; ks < 8; ++ks) {
        const int k0 = ks * 32 + kb * 8;
        const f4v a0 = *reinterpret_cast<const f4v*>(xA + k0);
        const f4v a1 = *reinterpret_cast<const f4v*>(xA + k0 + 4);
        const f4v b0 = *reinterpret_cast<const f4v*>(xB + k0);
        const f4v b1 = *reinterpret_cast<const f4v*>(xB + k0 + 4);
        union { s8v v; unsigned short u[8]; } fa, fb;
        #pragma unroll
        for (int j = 0; j < 4; ++j) {
            fa.u[j] = f2bf(a0[j]); fa.u[4 + j] = f2bf(a1[j]);
            fb.u[j] = f2bf(b0[j]); fb.u[4 + j] = f2bf(b1[j]);
        }
        xfA[ks] = fa.v; xfB[ks] = fb.v;
    }

    const int dA0 = deg0[rAc], dB0 = deg0[rBc], dA1 = deg1[rAc], dB1 = deg1[rBc];
    const float s0A = rsqrtf((float)(dA0 < 1 ? 1 : dA0));
    const float s0B = rsqrtf((float)(dB0 < 1 ? 1 : dB0));
    const float s1A = rsqrtf((float)(dA1 < 1 ? 1 : dA1));
    const float s1B = rsqrtf((float)(dB1 < 1 ? 1 : dB1));

    #pragma unroll 2
    for (int nt = 0; nt < 16; ++nt) {
        const __hip_bfloat16* w0p = Wt0 + (size_t)(nt * 16 + c) * DDIM + kb * 8;
        const __hip_bfloat16* w1p = Wt1 + (size_t)(nt * 16 + c) * DDIM + kb * 8;
        s8v wf0[8], wf1[8];
        #pragma unroll
        for (int ks = 0; ks < 8; ++ks) {
            wf0[ks] = *reinterpret_cast<const s8v*>(w0p + ks * 32);
            wf1[ks] = *reinterpret_cast<const s8v*>(w1p + ks * 32);
        }
        f4v a00 = (f4v){0.f,0.f,0.f,0.f}, a01 = a00, a10 = a00, a11 = a00;
        #pragma unroll
        for (int ks = 0; ks < 8; ++ks) {
            a00 = __builtin_amdgcn_mfma_f32_16x16x32_bf16(wf0[ks], xfA[ks], a00, 0, 0, 0);
            a10 = __builtin_amdgcn_mfma_f32_16x16x32_bf16(wf0[ks], xfB[ks], a10, 0, 0, 0);
            a01 = __builtin_amdgcn_mfma_f32_16x16x32_bf16(wf1[ks], xfA[ks], a01, 0, 0, 0);
            a11 = __builtin_amdgcn_mfma_f32_16x16x32_bf16(wf1[ks], xfB[ks], a11, 0, 0, 0);
        }
        const int col = nt * 16 + kb * 4;
        if (vA) {
            uint2 o0, o1;
            o0.x = pack2(a00[0] * s0A, a00[1] * s0A); o0.y = pack2(a00[2] * s0A, a00[3] * s0A);
            o1.x = pack2(a01[0] * s1A, a01[1] * s1A); o1.y = pack2(a01[2] * s1A, a01[3] * s1A);
            *reinterpret_cast<uint2*>(Y0 + (size_t)rA * DDIM + col) = o0;
            *reinterpret_cast<uint2*>(Y1 + (size_t)rA * DDIM + col) = o1;
        }
        if (vB) {
            uint2 o0, o1;
            o0.x = pack2(a10[0] * s0B, a10[1] * s0B); o0.y = pack2(a10[2] * s0B, a10[3] * s0B);
            o1.x = pack2(a11[0] * s1B, a11[1] * s1B); o1.y = pack2(a11[2] * s1B, a11[3] * s1B);
            *reinterpret_cast<uint2*>(Y0 + (size_t)rB * DDIM + col) = o0;
            *reinterpret_cast<uint2*>(Y1 + (size_t)rB * DDIM + col) = o1;
        }
    }
}

// ---------------- single-output GEMM ----------------
__global__ __launch_bounds__(256, 2) void gemm1_k(
    const float* __restrict__ X, const __hip_bfloat16* __restrict__ Wt0,
    const int* __restrict__ deg0, __hip_bfloat16* __restrict__ Y0, int M) {
    const int lane = threadIdx.x & 63, wid = threadIdx.x >> 6;
    const int c = lane & 15, kb = lane >> 4;
    const int rA = blockIdx.x * 128 + wid * 32 + c;
    const int rB = rA + 16;
    const bool vA = rA < M, vB = rB < M;
    const int rAc = vA ? rA : (M - 1), rBc = vB ? rB : (M - 1);

    s8v xfA[8], xfB[8];
    const float* xA = X + (size_t)rAc * DDIM;
    const float* xB = X + (size_t)rBc * DDIM;
    #pragma unroll
    for (int ks = 0; ks < 8; ++ks) {
        const int k0 = ks * 32 + kb * 8;
        const f4v a0 = *reinterpret_cast<const f4v*>(xA + k0);
        const f4v a1 = *reinterpret_cast<const f4v*>(xA + k0 + 4);
        const f4v b0 = *reinterpret_cast<const f4v*>(xB + k0);
        const f4v b1 = *reinterpret_cast<const f4v*>(xB + k0 + 4);
        union { s8v v; unsigned short u[8]; } fa, fb;
        #pragma unroll
        for (int j = 0; j < 4; ++j) {
            fa.u[j] = f2bf(a0[j]); fa.u[4 + j] = f2bf(a1[j]);
            fb.u[j] = f2bf(b0[j]); fb.u[4 + j] = f2bf(b1[j]);
        }
        xfA[ks] = fa.v; xfB[ks] = fb.v;
    }
    const int dA0 = deg0[rAc], dB0 = deg0[rBc];
    const float s0A = rsqrtf((float)(dA0 < 1 ? 1 : dA0));
    const float s0B = rsqrtf((float)(dB0 < 1 ? 1 : dB0));

    #pragma unroll 2
    for (int nt = 0; nt < 16; ++nt) {
        const __hip_bfloat16* w0p = Wt0 + (size_t)(nt * 16 + c) * DDIM + kb * 8;
        s8v wf0[8];
        #pragma unroll
        for (int ks = 0; ks < 8; ++ks) wf0[ks] = *reinterpret_cast<const s8v*>(w0p + ks * 32);
        f4v a00 = (f4v){0.f,0.f,0.f,0.f}, a10 = a00;
        #pragma unroll
        for (int ks = 0; ks < 8; ++ks) {
            a00 = __builtin_amdgcn_mfma_f32_16x16x32_bf16(wf0[ks], xfA[ks], a00, 0, 0, 0);
            a10 = __builtin_amdgcn_mfma_f32_16x16x32_bf16(wf0[ks], xfB[ks], a10, 0, 0, 0);
        }
        const int col = nt * 16 + kb * 4;
        if (vA) {
            uint2 o;
            o.x = pack2(a00[0] * s0A, a00[1] * s0A); o.y = pack2(a00[2] * s0A, a00[3] * s0A);
            *reinterpret_cast<uint2*>(Y0 + (size_t)rA * DDIM + col) = o;
        }
        if (vB) {
            uint2 o;
            o.x = pack2(a10[0] * s0B, a10[1] * s0B); o.y = pack2(a10[2] * s0B, a10[3] * s0B);
            *reinterpret_cast<uint2*>(Y0 + (size_t)rB * DDIM + col) = o;
        }
    }
}

// ---------------- column-sliced gather ----------------
// Wave layout: 16 edge-groups x 4 lanes x 16 B -> 16 edges in flight per load inst,
// each reading a 64 B slice of the Y row. Slice working set = 3.2 MB (L2-resident:
// grid is (rowBlocks, NSLICE), dispatch x-major so same-slice blocks run as a cohort).
__device__ __forceinline__ void segsum_slice(const unsigned* __restrict__ recs, int beg, int n,
                                             const __hip_bfloat16* __restrict__ Y,
                                             int lane, int g, int scol, f4v& a0, f4v& a1) {
    for (int j0 = 0; j0 < n; j0 += 64) {
        const int chunk = min(64, n - j0);
        unsigned rv = 0;
        if (lane < chunk) rv = recs[beg + j0 + lane];
        for (int t = 0; t < chunk; t += 16) {
            const int e = t + g;
            const unsigned r = __shfl(rv, e);
            if (e < chunk) {
                const uint4 v = *reinterpret_cast<const uint4*>(
                    Y + (size_t)(r & 0xffffu) * DDIM + scol);
                a0[0] += bf2f(v.x & 0xffffu); a0[1] += bf2f(v.x >> 16);
                a0[2] += bf2f(v.y & 0xffffu); a0[3] += bf2f(v.y >> 16);
                a1[0] += bf2f(v.z & 0xffffu); a1[1] += bf2f(v.z >> 16);
                a1[2] += bf2f(v.w & 0xffffu); a1[3] += bf2f(v.w >> 16);
            }
        }
    }
}

__global__ __launch_bounds__(256) void gather_slice_k(
    const unsigned* __restrict__ recs,
    const int* __restrict__ beg0, const int* __restrict__ cnt0,
    const __hip_bfloat16* __restrict__ Y0,
    const int* __restrict__ beg1, const int* __restrict__ cnt1,
    const __hip_bfloat16* __restrict__ Y1,          // beg1 == null -> single relation
    float* __restrict__ out, int n_dst) {
    const int lane = threadIdx.x & 63, wid = threadIdx.x >> 6;
    const int row = blockIdx.x * 4 + wid;
    if (row >= n_dst) return;
    const int g = lane >> 2;                        // edge group 0..15
    const int sub = lane & 3;                       // 16 B sub-slice 0..3
    const int scol = blockIdx.y * 32 + sub * 8;     // bf16 column of this lane's 16 B

    f4v t0 = (f4v){0.f,0.f,0.f,0.f}, t1 = t0;
    {
        f4v a0 = t0, a1 = t0;
        const int n0 = cnt0[row];
        segsum_slice(recs, beg0[row], n0, Y0, lane, g, scol, a0, a1);
        const float sc = rsqrtf((float)(n0 < 1 ? 1 : n0));
        t0 = a0 * sc; t1 = a1 * sc;
    }
    if (beg1 != nullptr) {
        f4v a0 = (f4v){0.f,0.f,0.f,0.f}, a1 = a0;
        const int n1 = cnt1[row];
        segsum_slice(recs, beg1[row], n1, Y1, lane, g, scol, a0, a1);
        const float sc = rsqrtf((float)(n1 < 1 ? 1 : n1));
        t0 += a0 * sc; t1 += a1 * sc;
    }

    // reduce over the 16 edge groups (lanes with equal sub)
    #pragma unroll
    for (int off = 4; off < 64; off <<= 1) {
        #pragma unroll
        for (int j = 0; j < 4; ++j) {
            t0[j] += __shfl_xor(t0[j], off);
            t1[j] += __shfl_xor(t1[j], off);
        }
    }
    if (g == 0) {   // lanes 0..3 hold the final slice sums
        float* op = out + (size_t)row * DDIM + scol;
        *reinterpret_cast<f4v*>(op) = t0;
        *reinterpret_cast<f4v*>(op + 4) = t1;
    }
}

// ---------------- in-place LayerNorm + bias + ReLU over both outputs ----------------
// Wave per row; row < N -> cell params, else gene. Read-modify-write of own row only.
__global__ __launch_bounds__(256) void ln_k(
    float* __restrict__ out,
    const float* __restrict__ gamma_c, const float* __restrict__ beta_c,
    const float* __restrict__ bias_c,
    const float* __restrict__ gamma_g, const float* __restrict__ beta_g,
    const float* __restrict__ bias_g, int N) {
    const int lane = threadIdx.x & 63, wid = threadIdx.x >> 6;
    const int row = blockIdx.x * 4 + wid;
    if (row >= 2 * N) return;
    const bool cell = row < N;
    const float* gamma = cell ? gamma_c : gamma_g;
    const float* beta  = cell ? beta_c  : beta_g;
    const float* bias  = cell ? bias_c  : bias_g;

    float* rp = out + (size_t)row * DDIM;
    const f4v a = reinterpret_cast<const f4v*>(rp)[lane];
    float s1 = a[0] + a[1] + a[2] + a[3];
    float s2 = a[0]*a[0] + a[1]*a[1] + a[2]*a[2] + a[3]*a[3];
    #pragma unroll
    for (int off = 1; off < 64; off <<= 1) {
        s1 += __shfl_xor(s1, off);
        s2 += __shfl_xor(s2, off);
    }
    const float mu = s1 * (1.f / 256.f);
    float var = s2 * (1.f / 256.f) - mu * mu;
    var = fmaxf(var, 0.f);
    const float rs = rsqrtf(var + 1e-5f);

    const f4v g  = reinterpret_cast<const f4v*>(gamma)[lane];
    const f4v be = reinterpret_cast<const f4v*>(beta)[lane];
    const f4v bb = reinterpret_cast<const f4v*>(bias)[lane];
    f4v o;
    #pragma unroll
    for (int j = 0; j < 4; ++j)
        o[j] = fmaxf((a[j] - mu) * rs * g[j] + be[j] + bb[j], 0.f);
    reinterpret_cast<f4v*>(rp)[lane] = o;
}

extern "C" void kernel_launch(void* const* d_in, const int* in_sizes, int n_in,
                              void* d_out, int out_size, void* d_ws, size_t ws_size,
                              hipStream_t stream) {
    const float* x_cell     = (const float*)d_in[0];
    const float* x_gene     = (const float*)d_in[1];
    const float* W_cg       = (const float*)d_in[2];
    const float* W_gc       = (const float*)d_in[3];
    const float* W_gg       = (const float*)d_in[4];
    const float* gamma_cell = (const float*)d_in[5];
    const float* beta_cell  = (const float*)d_in[6];
    const float* gamma_gene = (const float*)d_in[7];
    const float* beta_gene  = (const float*)d_in[8];
    const float* b_cell     = (const float*)d_in[9];
    const float* b_gene     = (const float*)d_in[10];
    const int* src_cg = (const int*)d_in[11];
    const int* dst_cg = (const int*)d_in[12];
    const int* src_gc = (const int*)d_in[13];
    const int* dst_gc = (const int*)d_in[14];
    const int* src_gg = (const int*)d_in[15];
    const int* dst_gg = (const int*)d_in[16];

    const int N = in_sizes[0] / DDIM;        // 50000
    const int E = in_sizes[11];              // 800000
    const int ncb = (N + 511) >> 9;          // 98 used coarse bins

    // ---- workspace layout (~47 MB) ----
    char* wsb = (char*)d_ws;
    size_t off = 0;
    __hip_bfloat16* Y_gc = (__hip_bfloat16*)(wsb + off); off += (size_t)N * DDIM * 2;           // 25.6 MB
    unsigned* recs = (unsigned*)(wsb + off);             off += (size_t)3 * NCPAD * CCAP * 4;   // 14.2 MB
    int* row_beg = (int*)(wsb + off);                    off += (size_t)3 * N * 4;              // 600 KB
    int* row_cnt = (int*)(wsb + off);                    off += (size_t)3 * N * 4;              // 600 KB
    int* cs      = (int*)(wsb + off);                    off += (size_t)3 * N * 4;              // 600 KB
    const size_t zeroOff = off;
    int* cs_shard = (int*)(wsb + off);                   off += (size_t)NSHARD * 3 * N * 4;     // 4.8 MB
    int* gcur     = (int*)(wsb + off);                   off += (size_t)3 * NCPAD * 4;          // 1.5 KB
    const size_t zeroBytes = off - zeroOff;
    __hip_bfloat16* Wt_gc = (__hip_bfloat16*)(wsb + off); off += (size_t)DDIM * DDIM * 2;
    __hip_bfloat16* Wt_cg = (__hip_bfloat16*)(wsb + off); off += (size_t)DDIM * DDIM * 2;
    __hip_bfloat16* Wt_gg = (__hip_bfloat16*)(wsb + off);

    int* cs_gc = cs, *cs_cg = cs + N, *cs_gg = cs + 2 * N;
    int* beg_gc = row_beg, *beg_cg = row_beg + N, *beg_gg = row_beg + 2 * N;
    int* cnt_gc = row_cnt, *cnt_cg = row_cnt + N, *cnt_gg = row_cnt + 2 * N;

    // Y_cg, Y_gg live in the d_out cell-half (bytes [0, 51.2 MB)); consumed by the
    // gene slice-gather (which writes only the gene half) before the cell gather
    // overwrites the cell half.
    float* out_cell = (float*)d_out;
    float* out_gene = out_cell + (size_t)N * DDIM;
    __hip_bfloat16* Y_cg = (__hip_bfloat16*)d_out;
    __hip_bfloat16* Y_gg = Y_cg + (size_t)N * DDIM;

    const int binBlocks  = (E + T1 - 1) / T1;
    const int gemmBlocks = (N + 127) / 128;
    const int rowBlocks  = (N + 3) / 4;

    transpose3_k<<<dim3(DDIM, 3), DDIM, 0, stream>>>(W_gc, W_cg, W_gg, Wt_gc, Wt_cg, Wt_gg);
    hipMemsetAsync(wsb + zeroOff, 0, zeroBytes, stream);

    // relations: 0=gc, 1=cg, 2=gg
    bin1_k<<<dim3(binBlocks, 3), 256, 0, stream>>>(src_gc, dst_gc, src_cg, dst_cg,
                                                   src_gg, dst_gg, cs_shard, gcur, recs, N, E);
    reduce_cs_k<<<(3 * N + 255) / 256, 256, 0, stream>>>(cs_shard, cs, 3 * N);
    sort_k<<<3 * ncb, 256, 0, stream>>>(recs, gcur, row_beg, row_cnt, N, ncb);

    gemm2_k<<<gemmBlocks, 256, 0, stream>>>(x_gene, Wt_gc, Wt_gg, cs_gc, cs_gg,
                                            Y_gc, Y_gg, N);
    gemm1_k<<<gemmBlocks, 256, 0, stream>>>(x_cell, Wt_cg, cs_cg, Y_cg, N);

    // gene: cg + gg fused slice-gather -> pre-LN f32 into out_gene
    gather_slice_k<<<dim3(rowBlocks, NSLICE), 256, 0, stream>>>(
        recs, beg_cg, cnt_cg, Y_cg, beg_gg, cnt_gg, Y_gg, out_gene, N);
    // cell: gc slice-gather -> pre-LN f32 into out_cell (clobbers consumed Y_cg/Y_gg)
    gather_slice_k<<<dim3(rowBlocks, NSLICE), 256, 0, stream>>>(
        recs, beg_gc, cnt_gc, Y_gc, nullptr, nullptr, nullptr, out_cell, N);

    // in-place LayerNorm + bias + ReLU over both halves
    ln_k<<<(2 * N + 3) / 4, 256, 0, stream>>>(out_cell,
                                              gamma_cell, beta_cell, b_cell,
                                              gamma_gene, beta_gene, b_gene, N);
}

// Round 12
// 424.659 us; speedup vs baseline: 1.5559x; 1.5559x over previous
//
#include <hip/hip_runtime.h>
#include <hip/hip_bf16.h>
#include <stdint.h>

#define DDIM 256
#define NSHARD 8          // shards for deg_out atomics
#define T1 4096           // edges per bin1 block
#define NCPAD 128         // padded coarse-bin count (dst>>9, 512 rows/bin)
#define CCAP 9216         // record capacity per (rel, coarse bin); mean 8192, +11 sigma

typedef short s8v __attribute__((ext_vector_type(8)));
typedef float f4v __attribute__((ext_vector_type(4)));

__device__ __forceinline__ float bf2f(unsigned u) { return __uint_as_float(u << 16); }
__device__ __forceinline__ unsigned short f2bf(float f) {
    __hip_bfloat16 h = __float2bfloat16(f);
    return *reinterpret_cast<unsigned short*>(&h);
}
__device__ __forceinline__ unsigned pack2(float a, float b) {
    return (unsigned)f2bf(a) | ((unsigned)f2bf(b) << 16);
}

// ---------------- fused W transpose + cast: T[n][k] = bf16(W[k][n]) ----------------
__global__ void transpose3_k(const float* __restrict__ W0, const float* __restrict__ W1,
                             const float* __restrict__ W2, __hip_bfloat16* __restrict__ T0,
                             __hip_bfloat16* __restrict__ T1v, __hip_bfloat16* __restrict__ T2) {
    const float* W = (blockIdx.y == 0) ? W0 : (blockIdx.y == 1) ? W1 : W2;
    __hip_bfloat16* T = (blockIdx.y == 0) ? T0 : (blockIdx.y == 1) ? T1v : T2;
    T[blockIdx.x * DDIM + threadIdx.x] = __float2bfloat16(W[threadIdx.x * DDIM + blockIdx.x]);
}

// ---------------- pass 1: LDS-staged coarse binning (dense segment writes) ----------------
// record = src | (dst&511)<<16 | bin<<25 ; bin = dst>>9.
__global__ __launch_bounds__(256) void bin1_k(
    const int* __restrict__ s0, const int* __restrict__ d0,
    const int* __restrict__ s1, const int* __restrict__ d1,
    const int* __restrict__ s2, const int* __restrict__ d2,
    int* __restrict__ cs_shard,      // [NSHARD][3N]
    int* __restrict__ gcur,          // [3][NCPAD]
    unsigned* __restrict__ recs,     // [3][NCPAD][CCAP]
    int N, int E) {
    __shared__ unsigned stage[T1];           // 16 KB
    __shared__ int hcnt[NCPAD], hoff[NCPAD], lbase[NCPAD], lcur[NCPAD];
    const int t = threadIdx.x;
    const int rel = blockIdx.y;
    const int* s = (rel == 0) ? s0 : (rel == 1) ? s1 : s2;
    const int* d = (rel == 0) ? d0 : (rel == 1) ? d1 : d2;
    const int e0 = blockIdx.x * T1;
    const int n = min(T1, E - e0);
    int* csb = cs_shard + ((size_t)(blockIdx.x & (NSHARD - 1)) * 3 + rel) * N;

    if (t < NCPAD) { hcnt[t] = 0; lcur[t] = 0; }
    __syncthreads();

    int ssr[T1 / 256], ddr[T1 / 256];
    #pragma unroll
    for (int k = 0; k < T1 / 256; ++k) {
        const int li = k * 256 + t;
        const bool v = li < n;
        ssr[k] = v ? s[e0 + li] : -1;
        ddr[k] = v ? d[e0 + li] : -1;
        if (v) {
            atomicAdd(&hcnt[ddr[k] >> 9], 1);
            atomicAdd(&csb[ssr[k]], 1);
        }
    }
    __syncthreads();

    if (t < 64) {
        const int a0 = hcnt[2 * t], a1 = hcnt[2 * t + 1];
        const int sum = a0 + a1;
        int incl = sum;
        #pragma unroll
        for (int off = 1; off < 64; off <<= 1) {
            const int u = __shfl_up(incl, off);
            if (t >= off) incl += u;
        }
        const int excl = incl - sum;
        hoff[2 * t] = excl;
        hoff[2 * t + 1] = excl + a0;
    }
    __syncthreads();
    if (t < NCPAD) lbase[t] = atomicAdd(&gcur[rel * NCPAD + t], hcnt[t]);
    __syncthreads();

    #pragma unroll
    for (int k = 0; k < T1 / 256; ++k) {
        if (ddr[k] >= 0) {
            const int b = ddr[k] >> 9;
            const int p = atomicAdd(&lcur[b], 1);
            stage[hoff[b] + p] = (unsigned)ssr[k] | ((unsigned)(ddr[k] & 511) << 16)
                                 | ((unsigned)b << 25);
        }
    }
    __syncthreads();

    for (int i = t; i < n; i += 256) {
        const unsigned r = stage[i];
        const int b = (int)(r >> 25);
        const int pos = lbase[b] + (i - hoff[b]);
        if (pos < CCAP)
            recs[((size_t)rel * NCPAD + b) * CCAP + pos] = r & 0x1FFFFFFu;
    }
}

// ---------------- deg_out from shards, inline ----------------
__device__ __forceinline__ int deg_sum(const int* __restrict__ cs_shard, int rel, int r, int N) {
    int v = 0;
    #pragma unroll
    for (int s = 0; s < NSHARD; ++s) v += cs_shard[((size_t)s * 3 + rel) * N + r];
    return v;
}

// ---------------- sort body: per-coarse-bin LDS counting sort by dst row ----------------
__device__ void sort_body(int sb, unsigned* __restrict__ recs, const int* __restrict__ gcur,
                          int* __restrict__ row_beg, int* __restrict__ row_cnt,
                          int N, int ncb) {
    __shared__ unsigned stage[CCAP];     // 36 KB
    __shared__ int rc[512], ro[512], rcur[512];
    const int t = threadIdx.x;
    const int rel = sb / ncb, bin = sb % ncb;
    const size_t base = ((size_t)rel * NCPAD + bin) * CCAP;
    const int n = min(gcur[rel * NCPAD + bin], CCAP);

    for (int i = t; i < 512; i += 256) rc[i] = 0;
    __syncthreads();
    for (int i = t; i < n; i += 256) {
        const unsigned r = recs[base + i];
        stage[i] = r;
        atomicAdd(&rc[(r >> 16) & 511], 1);
    }
    __syncthreads();
    if (t < 64) {
        int v[8], p[8], sum = 0;
        #pragma unroll
        for (int j = 0; j < 8; ++j) { v[j] = rc[t * 8 + j]; p[j] = sum; sum += v[j]; }
        int incl = sum;
        #pragma unroll
        for (int off = 1; off < 64; off <<= 1) {
            const int u = __shfl_up(incl, off);
            if (t >= off) incl += u;
        }
        const int excl = incl - sum;
        #pragma unroll
        for (int j = 0; j < 8; ++j) { ro[t * 8 + j] = excl + p[j]; rcur[t * 8 + j] = excl + p[j]; }
    }
    __syncthreads();
    for (int i = t; i < 512; i += 256) {
        const int grow = bin * 512 + i;
        if (grow < N) {
            row_cnt[(size_t)rel * N + grow] = rc[i];
            row_beg[(size_t)rel * N + grow] = (int)(base + ro[i]);
        }
    }
    for (int i = t; i < n; i += 256) {
        const unsigned r = stage[i];
        const int pos = atomicAdd(&rcur[(r >> 16) & 511], 1);
        recs[base + pos] = r & 0xffffu;
    }
}

// ---------------- gemm bodies ----------------
__device__ void gemm2_body(int gb, const float* __restrict__ X,
                           const __hip_bfloat16* __restrict__ Wt0,
                           const __hip_bfloat16* __restrict__ Wt1,
                           const int* __restrict__ cs_shard, int rel0, int rel1,
                           __hip_bfloat16* __restrict__ Y0, __hip_bfloat16* __restrict__ Y1,
                           int M, int N) {
    const int lane = threadIdx.x & 63, wid = threadIdx.x >> 6;
    const int c = lane & 15, kb = lane >> 4;
    const int rA = gb * 128 + wid * 32 + c;
    const int rB = rA + 16;
    const bool vA = rA < M, vB = rB < M;
    const int rAc = vA ? rA : (M - 1), rBc = vB ? rB : (M - 1);

    s8v xfA[8], xfB[8];
    const float* xA = X + (size_t)rAc * DDIM;
    const float* xB = X + (size_t)rBc * DDIM;
    #pragma unroll
    for (int ks = 0; ks < 8; ++ks) {
        const int k0 = ks * 32 + kb * 8;
        const f4v a0 = *reinterpret_cast<const f4v*>(xA + k0);
        const f4v a1 = *reinterpret_cast<const f4v*>(xA + k0 + 4);
        const f4v b0 = *reinterpret_cast<const f4v*>(xB + k0);
        const f4v b1 = *reinterpret_cast<const f4v*>(xB + k0 + 4);
        union { s8v v; unsigned short u[8]; } fa, fb;
        #pragma unroll
        for (int j = 0; j < 4; ++j) {
            fa.u[j] = f2bf(a0[j]); fa.u[4 + j] = f2bf(a1[j]);
            fb.u[j] = f2bf(b0[j]); fb.u[4 + j] = f2bf(b1[j]);
        }
        xfA[ks] = fa.v; xfB[ks] = fb.v;
    }

    const int dA0 = deg_sum(cs_shard, rel0, rAc, N), dB0 = deg_sum(cs_shard, rel0, rBc, N);
    const int dA1 = deg_sum(cs_shard, rel1, rAc, N), dB1 = deg_sum(cs_shard, rel1, rBc, N);
    const float s0A = rsqrtf((float)(dA0 < 1 ? 1 : dA0));
    const float s0B = rsqrtf((float)(dB0 < 1 ? 1 : dB0));
    const float s1A = rsqrtf((float)(dA1 < 1 ? 1 : dA1));
    const float s1B = rsqrtf((float)(dB1 < 1 ? 1 : dB1));

    #pragma unroll 2
    for (int nt = 0; nt < 16; ++nt) {
        const __hip_bfloat16* w0p = Wt0 + (size_t)(nt * 16 + c) * DDIM + kb * 8;
        const __hip_bfloat16* w1p = Wt1 + (size_t)(nt * 16 + c) * DDIM + kb * 8;
        s8v wf0[8], wf1[8];
        #pragma unroll
        for (int ks = 0; ks < 8; ++ks) {
            wf0[ks] = *reinterpret_cast<const s8v*>(w0p + ks * 32);
            wf1[ks] = *reinterpret_cast<const s8v*>(w1p + ks * 32);
        }
        f4v a00 = (f4v){0.f,0.f,0.f,0.f}, a01 = a00, a10 = a00, a11 = a00;
        #pragma unroll
        for (int ks = 0; ks < 8; ++ks) {
            a00 = __builtin_amdgcn_mfma_f32_16x16x32_bf16(wf0[ks], xfA[ks], a00, 0, 0, 0);
            a10 = __builtin_amdgcn_mfma_f32_16x16x32_bf16(wf0[ks], xfB[ks], a10, 0, 0, 0);
            a01 = __builtin_amdgcn_mfma_f32_16x16x32_bf16(wf1[ks], xfA[ks], a01, 0, 0, 0);
            a11 = __builtin_amdgcn_mfma_f32_16x16x32_bf16(wf1[ks], xfB[ks], a11, 0, 0, 0);
        }
        const int col = nt * 16 + kb * 4;
        if (vA) {
            uint2 o0, o1;
            o0.x = pack2(a00[0] * s0A, a00[1] * s0A); o0.y = pack2(a00[2] * s0A, a00[3] * s0A);
            o1.x = pack2(a01[0] * s1A, a01[1] * s1A); o1.y = pack2(a01[2] * s1A, a01[3] * s1A);
            *reinterpret_cast<uint2*>(Y0 + (size_t)rA * DDIM + col) = o0;
            *reinterpret_cast<uint2*>(Y1 + (size_t)rA * DDIM + col) = o1;
        }
        if (vB) {
            uint2 o0, o1;
            o0.x = pack2(a10[0] * s0B, a10[1] * s0B); o0.y = pack2(a10[2] * s0B, a10[3] * s0B);
            o1.x = pack2(a11[0] * s1B, a11[1] * s1B); o1.y = pack2(a11[2] * s1B, a11[3] * s1B);
            *reinterpret_cast<uint2*>(Y0 + (size_t)rB * DDIM + col) = o0;
            *reinterpret_cast<uint2*>(Y1 + (size_t)rB * DDIM + col) = o1;
        }
    }
}

__device__ void gemm1_body(int gb, const float* __restrict__ X,
                           const __hip_bfloat16* __restrict__ Wt0,
                           const int* __restrict__ cs_shard, int rel0,
                           __hip_bfloat16* __restrict__ Y0, int M, int N) {
    const int lane = threadIdx.x & 63, wid = threadIdx.x >> 6;
    const int c = lane & 15, kb = lane >> 4;
    const int rA = gb * 128 + wid * 32 + c;
    const int rB = rA + 16;
    const bool vA = rA < M, vB = rB < M;
    const int rAc = vA ? rA : (M - 1), rBc = vB ? rB : (M - 1);

    s8v xfA[8], xfB[8];
    const float* xA = X + (size_t)rAc * DDIM;
    const float* xB = X + (size_t)rBc * DDIM;
    #pragma unroll
    for (int ks = 0; ks < 8; ++ks) {
        const int k0 = ks * 32 + kb * 8;
        const f4v a0 = *reinterpret_cast<const f4v*>(xA + k0);
        const f4v a1 = *reinterpret_cast<const f4v*>(xA + k0 + 4);
        const f4v b0 = *reinterpret_cast<const f4v*>(xB + k0);
        const f4v b1 = *reinterpret_cast<const f4v*>(xB + k0 + 4);
        union { s8v v; unsigned short u[8]; } fa, fb;
        #pragma unroll
        for (int j = 0; j < 4; ++j) {
            fa.u[j] = f2bf(a0[j]); fa.u[4 + j] = f2bf(a1[j]);
            fb.u[j] = f2bf(b0[j]); fb.u[4 + j] = f2bf(b1[j]);
        }
        xfA[ks] = fa.v; xfB[ks] = fb.v;
    }
    const int dA0 = deg_sum(cs_shard, rel0, rAc, N), dB0 = deg_sum(cs_shard, rel0, rBc, N);
    const float s0A = rsqrtf((float)(dA0 < 1 ? 1 : dA0));
    const float s0B = rsqrtf((float)(dB0 < 1 ? 1 : dB0));

    #pragma unroll 2
    for (int nt = 0; nt < 16; ++nt) {
        const __hip_bfloat16* w0p = Wt0 + (size_t)(nt * 16 + c) * DDIM + kb * 8;
        s8v wf0[8];
        #pragma unroll
        for (int ks = 0; ks < 8; ++ks) wf0[ks] = *reinterpret_cast<const s8v*>(w0p + ks * 32);
        f4v a00 = (f4v){0.f,0.f,0.f,0.f}, a10 = a00;
        #pragma unroll
        for (int ks = 0; ks < 8; ++ks) {
            a00 = __builtin_amdgcn_mfma_f32_16x16x32_bf16(wf0[ks], xfA[ks], a00, 0, 0, 0);
            a10 = __builtin_amdgcn_mfma_f32_16x16x32_bf16(wf0[ks], xfB[ks], a10, 0, 0, 0);
        }
        const int col = nt * 16 + kb * 4;
        if (vA) {
            uint2 o;
            o.x = pack2(a00[0] * s0A, a00[1] * s0A); o.y = pack2(a00[2] * s0A, a00[3] * s0A);
            *reinterpret_cast<uint2*>(Y0 + (size_t)rA * DDIM + col) = o;
        }
        if (vB) {
            uint2 o;
            o.x = pack2(a10[0] * s0B, a10[1] * s0B); o.y = pack2(a10[2] * s0B, a10[3] * s0B);
            *reinterpret_cast<uint2*>(Y0 + (size_t)rB * DDIM + col) = o;
        }
    }
}

// ---------------- mid: sort + both GEMMs in one dispatch (all depend only on bin1) ----------------
__global__ __launch_bounds__(256, 2) void mid_k(
    unsigned* __restrict__ recs, const int* __restrict__ gcur,
    int* __restrict__ row_beg, int* __restrict__ row_cnt,
    const float* __restrict__ x_gene, const float* __restrict__ x_cell,
    const __hip_bfloat16* __restrict__ Wt_gc, const __hip_bfloat16* __restrict__ Wt_gg,
    const __hip_bfloat16* __restrict__ Wt_cg,
    const int* __restrict__ cs_shard,
    __hip_bfloat16* __restrict__ Y_gc, __hip_bfloat16* __restrict__ Y_gg,
    __hip_bfloat16* __restrict__ Y_cg,
    int N, int ncb, int gemmBlocks) {
    const int nSort = 3 * ncb;
    const int bid = blockIdx.x;
    if (bid < nSort) {
        sort_body(bid, recs, gcur, row_beg, row_cnt, N, ncb);
        return;
    }
    const int g = bid - nSort;
    if (g < gemmBlocks)
        gemm2_body(g, x_gene, Wt_gc, Wt_gg, cs_shard, 0, 2, Y_gc, Y_gg, N, N);
    else
        gemm1_body(g - gemmBlocks, x_cell, Wt_cg, cs_shard, 1, Y_cg, N, N);
}

// ---------------- gather: 2 rows per wave, interleaved dual-segment loads ----------------
__device__ __forceinline__ void addv(f4v& a, uint2 v) {
    a[0] += bf2f(v.x & 0xffffu);
    a[1] += bf2f(v.x >> 16);
    a[2] += bf2f(v.y & 0xffffu);
    a[3] += bf2f(v.y >> 16);
}

// Two independent segments aggregated with explicitly batched 4+4 loads so up to
// 8 loads stay in flight (the mechanism behind round-9's gene/cell asymmetry).
__device__ __forceinline__ void segsum2(const unsigned* __restrict__ recs,
                                        int begA, int nA, int begB, int nB,
                                        const __hip_bfloat16* __restrict__ Y,
                                        int lane, f4v& aA, f4v& aB) {
    const int nmax = nA > nB ? nA : nB;
    for (int j0 = 0; j0 < nmax; j0 += 64) {
        const int cA = nA - j0, cB = nB - j0;
        unsigned rvA = 0, rvB = 0;
        if (lane < cA) rvA = recs[begA + j0 + lane];
        if (lane < cB) rvB = recs[begB + j0 + lane];
        const int eA = cA > 64 ? 64 : cA;
        const int eB = cB > 64 ? 64 : cB;
        const int cm = eA > eB ? eA : eB;
        for (int t = 0; t < cm; t += 4) {
            uint2 vA[4], vB[4];
            const int kA = eA - t, kB = eB - t;   // wave-uniform guards
            #pragma unroll
            for (int i = 0; i < 4; ++i)
                if (i < kA) vA[i] = reinterpret_cast<const uint2*>(
                    Y + (size_t)(__shfl(rvA, t + i) & 0xffffu) * DDIM)[lane];
            #pragma unroll
            for (int i = 0; i < 4; ++i)
                if (i < kB) vB[i] = reinterpret_cast<const uint2*>(
                    Y + (size_t)(__shfl(rvB, t + i) & 0xffffu) * DDIM)[lane];
            #pragma unroll
            for (int i = 0; i < 4; ++i) if (i < kA) addv(aA, vA[i]);
            #pragma unroll
            for (int i = 0; i < 4; ++i) if (i < kB) addv(aB, vB[i]);
        }
    }
}

__global__ __launch_bounds__(256, 4) void gather_ln_k(
    const unsigned* __restrict__ recs,
    const int* __restrict__ beg0, const int* __restrict__ cnt0,
    const __hip_bfloat16* __restrict__ Y0,
    const int* __restrict__ beg1, const int* __restrict__ cnt1,
    const __hip_bfloat16* __restrict__ Y1,          // beg1 == null -> single relation
    const float* __restrict__ gamma, const float* __restrict__ beta,
    const float* __restrict__ bias, float* __restrict__ out, int n_dst) {
    const int lane = threadIdx.x & 63, wid = threadIdx.x >> 6;
    const int rA = (blockIdx.x * 4 + wid) * 2;
    if (rA >= n_dst) return;
    const int rB = rA + 1;
    const bool hasB = rB < n_dst;
    const int rBc = hasB ? rB : rA;

    f4v aA = (f4v){0.f,0.f,0.f,0.f}, aB = aA;
    const int n0A = cnt0[rA], n0B = hasB ? cnt0[rBc] : 0;
    segsum2(recs, beg0[rA], n0A, beg0[rBc], n0B, Y0, lane, aA, aB);
    aA *= rsqrtf((float)(n0A < 1 ? 1 : n0A));
    aB *= rsqrtf((float)(n0B < 1 ? 1 : n0B));
    if (beg1 != nullptr) {
        f4v bA = (f4v){0.f,0.f,0.f,0.f}, bB = bA;
        const int n1A = cnt1[rA], n1B = hasB ? cnt1[rBc] : 0;
        segsum2(recs, beg1[rA], n1A, beg1[rBc], n1B, Y1, lane, bA, bB);
        aA += bA * rsqrtf((float)(n1A < 1 ? 1 : n1A));
        aB += bB * rsqrtf((float)(n1B < 1 ? 1 : n1B));
    }

    // joint LN reduce for both rows (4 scalars through one shfl tree)
    float s1A = aA[0]+aA[1]+aA[2]+aA[3];
    float s2A = aA[0]*aA[0]+aA[1]*aA[1]+aA[2]*aA[2]+aA[3]*aA[3];
    float s1B = aB[0]+aB[1]+aB[2]+aB[3];
    float s2B = aB[0]*aB[0]+aB[1]*aB[1]+aB[2]*aB[2]+aB[3]*aB[3];
    #pragma unroll
    for (int off = 1; off < 64; off <<= 1) {
        s1A += __shfl_xor(s1A, off);
        s2A += __shfl_xor(s2A, off);
        s1B += __shfl_xor(s1B, off);
        s2B += __shfl_xor(s2B, off);
    }
    const float muA = s1A * (1.f / 256.f);
    const float muB = s1B * (1.f / 256.f);
    const float rsA = rsqrtf(fmaxf(s2A * (1.f / 256.f) - muA * muA, 0.f) + 1e-5f);
    const float rsB = rsqrtf(fmaxf(s2B * (1.f / 256.f) - muB * muB, 0.f) + 1e-5f);

    const f4v g  = reinterpret_cast<const f4v*>(gamma)[lane];
    const f4v be = reinterpret_cast<const f4v*>(beta)[lane];
    const f4v bb = reinterpret_cast<const f4v*>(bias)[lane];
    f4v oA, oB;
    #pragma unroll
    for (int j = 0; j < 4; ++j) {
        oA[j] = fmaxf((aA[j] - muA) * rsA * g[j] + be[j] + bb[j], 0.f);
        oB[j] = fmaxf((aB[j] - muB) * rsB * g[j] + be[j] + bb[j], 0.f);
    }
    reinterpret_cast<f4v*>(out + (size_t)rA * DDIM)[lane] = oA;
    if (hasB)
        reinterpret_cast<f4v*>(out + (size_t)rB * DDIM)[lane] = oB;
}

extern "C" void kernel_launch(void* const* d_in, const int* in_sizes, int n_in,
                              void* d_out, int out_size, void* d_ws, size_t ws_size,
                              hipStream_t stream) {
    const float* x_cell     = (const float*)d_in[0];
    const float* x_gene     = (const float*)d_in[1];
    const float* W_cg       = (const float*)d_in[2];
    const float* W_gc       = (const float*)d_in[3];
    const float* W_gg       = (const float*)d_in[4];
    const float* gamma_cell = (const float*)d_in[5];
    const float* beta_cell  = (const float*)d_in[6];
    const float* gamma_gene = (const float*)d_in[7];
    const float* beta_gene  = (const float*)d_in[8];
    const float* b_cell     = (const float*)d_in[9];
    const float* b_gene     = (const float*)d_in[10];
    const int* src_cg = (const int*)d_in[11];
    const int* dst_cg = (const int*)d_in[12];
    const int* src_gc = (const int*)d_in[13];
    const int* dst_gc = (const int*)d_in[14];
    const int* src_gg = (const int*)d_in[15];
    const int* dst_gg = (const int*)d_in[16];

    const int N = in_sizes[0] / DDIM;        // 50000
    const int E = in_sizes[11];              // 800000
    const int ncb = (N + 511) >> 9;          // 98 used coarse bins

    // ---- workspace layout (~46 MB) ----
    char* wsb = (char*)d_ws;
    size_t off = 0;
    __hip_bfloat16* Y_gc = (__hip_bfloat16*)(wsb + off); off += (size_t)N * DDIM * 2;           // 25.6 MB
    unsigned* recs = (unsigned*)(wsb + off);             off += (size_t)3 * NCPAD * CCAP * 4;   // 14.2 MB
    int* row_beg = (int*)(wsb + off);                    off += (size_t)3 * N * 4;              // 600 KB
    int* row_cnt = (int*)(wsb + off);                    off += (size_t)3 * N * 4;              // 600 KB
    const size_t zeroOff = off;
    int* cs_shard = (int*)(wsb + off);                   off += (size_t)NSHARD * 3 * N * 4;     // 4.8 MB
    int* gcur     = (int*)(wsb + off);                   off += (size_t)3 * NCPAD * 4;          // 1.5 KB
    const size_t zeroBytes = off - zeroOff;
    __hip_bfloat16* Wt_gc = (__hip_bfloat16*)(wsb + off); off += (size_t)DDIM * DDIM * 2;
    __hip_bfloat16* Wt_cg = (__hip_bfloat16*)(wsb + off); off += (size_t)DDIM * DDIM * 2;
    __hip_bfloat16* Wt_gg = (__hip_bfloat16*)(wsb + off);

    int* beg_gc = row_beg, *beg_cg = row_beg + N, *beg_gg = row_beg + 2 * N;
    int* cnt_gc = row_cnt, *cnt_cg = row_cnt + N, *cnt_gg = row_cnt + 2 * N;

    // Y_cg, Y_gg live in the d_out cell-half; consumed by the gene gather before
    // the cell gather overwrites that region with the final cell output.
    float* out_cell = (float*)d_out;
    float* out_gene = out_cell + (size_t)N * DDIM;
    __hip_bfloat16* Y_cg = (__hip_bfloat16*)d_out;
    __hip_bfloat16* Y_gg = Y_cg + (size_t)N * DDIM;

    const int binBlocks  = (E + T1 - 1) / T1;
    const int gemmBlocks = (N + 127) / 128;
    const int gatherBlocks = (N + 7) / 8;    // 2 rows per wave, 4 waves per block

    transpose3_k<<<dim3(DDIM, 3), DDIM, 0, stream>>>(W_gc, W_cg, W_gg, Wt_gc, Wt_cg, Wt_gg);
    hipMemsetAsync(wsb + zeroOff, 0, zeroBytes, stream);

    // relations: 0=gc, 1=cg, 2=gg
    bin1_k<<<dim3(binBlocks, 3), 256, 0, stream>>>(src_gc, dst_gc, src_cg, dst_cg,
                                                   src_gg, dst_gg, cs_shard, gcur, recs, N, E);

    // sort + gemm2 + gemm1 in one dispatch (independent after bin1)
    mid_k<<<3 * ncb + 2 * gemmBlocks, 256, 0, stream>>>(
        recs, gcur, row_beg, row_cnt, x_gene, x_cell,
        Wt_gc, Wt_gg, Wt_cg, cs_shard, Y_gc, Y_gg, Y_cg, N, ncb, gemmBlocks);

    // gene: cg + gg fused gather + LN
    gather_ln_k<<<gatherBlocks, 256, 0, stream>>>(recs, beg_cg, cnt_cg, Y_cg,
                                                  beg_gg, cnt_gg, Y_gg,
                                                  gamma_gene, beta_gene, b_gene, out_gene, N);
    // cell: gc gather + LN (overwrites Y_cg/Y_gg region)
    gather_ln_k<<<gatherBlocks, 256, 0, stream>>>(recs, beg_gc, cnt_gc, Y_gc,
                                                  nullptr, nullptr, nullptr,
                                                  gamma_cell, beta_cell, b_cell, out_cell, N);
}

// Round 13
// 404.935 us; speedup vs baseline: 1.6317x; 1.0487x over previous
//
#include <hip/hip_runtime.h>
#include <hip/hip_bf16.h>
#include <stdint.h>

#define DDIM 256
#define NSHARD 8          // shards for deg_out atomics
#define T1 4096           // edges per bin1 block
#define NCPAD 128         // padded coarse-bin count (dst>>9, 512 rows/bin)
#define CCAP 9216         // record capacity per (rel, coarse bin); mean 8192, +11 sigma

typedef short s8v __attribute__((ext_vector_type(8)));
typedef float f4v __attribute__((ext_vector_type(4)));

__device__ __forceinline__ float bf2f(unsigned u) { return __uint_as_float(u << 16); }
__device__ __forceinline__ unsigned short f2bf(float f) {
    __hip_bfloat16 h = __float2bfloat16(f);
    return *reinterpret_cast<unsigned short*>(&h);
}
__device__ __forceinline__ unsigned pack2(float a, float b) {
    return (unsigned)f2bf(a) | ((unsigned)f2bf(b) << 16);
}

// ---------------- fused W transpose + cast: T[n][k] = bf16(W[k][n]) ----------------
__global__ void transpose3_k(const float* __restrict__ W0, const float* __restrict__ W1,
                             const float* __restrict__ W2, __hip_bfloat16* __restrict__ T0,
                             __hip_bfloat16* __restrict__ T1v, __hip_bfloat16* __restrict__ T2) {
    const float* W = (blockIdx.y == 0) ? W0 : (blockIdx.y == 1) ? W1 : W2;
    __hip_bfloat16* T = (blockIdx.y == 0) ? T0 : (blockIdx.y == 1) ? T1v : T2;
    T[blockIdx.x * DDIM + threadIdx.x] = __float2bfloat16(W[threadIdx.x * DDIM + blockIdx.x]);
}

// ---------------- pass 1: LDS-staged coarse binning (dense segment writes) ----------------
// record = src | (dst&511)<<16 | bin<<25 ; bin = dst>>9.
__global__ __launch_bounds__(256) void bin1_k(
    const int* __restrict__ s0, const int* __restrict__ d0,
    const int* __restrict__ s1, const int* __restrict__ d1,
    const int* __restrict__ s2, const int* __restrict__ d2,
    int* __restrict__ cs_shard,      // [NSHARD][3N]
    int* __restrict__ gcur,          // [3][NCPAD]
    unsigned* __restrict__ recs,     // [3][NCPAD][CCAP]
    int N, int E) {
    __shared__ unsigned stage[T1];           // 16 KB
    __shared__ int hcnt[NCPAD], hoff[NCPAD], lbase[NCPAD], lcur[NCPAD];
    const int t = threadIdx.x;
    const int rel = blockIdx.y;
    const int* s = (rel == 0) ? s0 : (rel == 1) ? s1 : s2;
    const int* d = (rel == 0) ? d0 : (rel == 1) ? d1 : d2;
    const int e0 = blockIdx.x * T1;
    const int n = min(T1, E - e0);
    int* csb = cs_shard + ((size_t)(blockIdx.x & (NSHARD - 1)) * 3 + rel) * N;

    if (t < NCPAD) { hcnt[t] = 0; lcur[t] = 0; }
    __syncthreads();

    int ssr[T1 / 256], ddr[T1 / 256];
    #pragma unroll
    for (int k = 0; k < T1 / 256; ++k) {
        const int li = k * 256 + t;
        const bool v = li < n;
        ssr[k] = v ? s[e0 + li] : -1;
        ddr[k] = v ? d[e0 + li] : -1;
        if (v) {
            atomicAdd(&hcnt[ddr[k] >> 9], 1);
            atomicAdd(&csb[ssr[k]], 1);
        }
    }
    __syncthreads();

    if (t < 64) {
        const int a0 = hcnt[2 * t], a1 = hcnt[2 * t + 1];
        const int sum = a0 + a1;
        int incl = sum;
        #pragma unroll
        for (int off = 1; off < 64; off <<= 1) {
            const int u = __shfl_up(incl, off);
            if (t >= off) incl += u;
        }
        const int excl = incl - sum;
        hoff[2 * t] = excl;
        hoff[2 * t + 1] = excl + a0;
    }
    __syncthreads();
    if (t < NCPAD) lbase[t] = atomicAdd(&gcur[rel * NCPAD + t], hcnt[t]);
    __syncthreads();

    #pragma unroll
    for (int k = 0; k < T1 / 256; ++k) {
        if (ddr[k] >= 0) {
            const int b = ddr[k] >> 9;
            const int p = atomicAdd(&lcur[b], 1);
            stage[hoff[b] + p] = (unsigned)ssr[k] | ((unsigned)(ddr[k] & 511) << 16)
                                 | ((unsigned)b << 25);
        }
    }
    __syncthreads();

    for (int i = t; i < n; i += 256) {
        const unsigned r = stage[i];
        const int b = (int)(r >> 25);
        const int pos = lbase[b] + (i - hoff[b]);
        if (pos < CCAP)
            recs[((size_t)rel * NCPAD + b) * CCAP + pos] = r & 0x1FFFFFFu;
    }
}

// ---------------- fold sharded deg_out ----------------
__global__ void reduce_cs_k(const int* __restrict__ cs_shard, int* __restrict__ cs, int n3) {
    const int i = blockIdx.x * blockDim.x + threadIdx.x;
    if (i >= n3) return;
    int v = 0;
    #pragma unroll
    for (int s = 0; s < NSHARD; ++s) v += cs_shard[(size_t)s * n3 + i];
    cs[i] = v;
}

// ---------------- pass 2: per-coarse-bin LDS counting sort by dst row ----------------
__global__ __launch_bounds__(256) void sort_k(
    unsigned* __restrict__ recs, const int* __restrict__ gcur,
    int* __restrict__ row_beg, int* __restrict__ row_cnt, int N, int ncb) {
    __shared__ unsigned stage[CCAP];     // 36 KB
    __shared__ int rc[512], ro[512], rcur[512];
    const int t = threadIdx.x;
    const int rel = blockIdx.x / ncb, bin = blockIdx.x % ncb;
    const size_t base = ((size_t)rel * NCPAD + bin) * CCAP;
    const int n = min(gcur[rel * NCPAD + bin], CCAP);

    for (int i = t; i < 512; i += 256) rc[i] = 0;
    __syncthreads();
    for (int i = t; i < n; i += 256) {
        const unsigned r = recs[base + i];
        stage[i] = r;
        atomicAdd(&rc[(r >> 16) & 511], 1);
    }
    __syncthreads();
    if (t < 64) {
        int v[8], p[8], sum = 0;
        #pragma unroll
        for (int j = 0; j < 8; ++j) { v[j] = rc[t * 8 + j]; p[j] = sum; sum += v[j]; }
        int incl = sum;
        #pragma unroll
        for (int off = 1; off < 64; off <<= 1) {
            const int u = __shfl_up(incl, off);
            if (t >= off) incl += u;
        }
        const int excl = incl - sum;
        #pragma unroll
        for (int j = 0; j < 8; ++j) { ro[t * 8 + j] = excl + p[j]; rcur[t * 8 + j] = excl + p[j]; }
    }
    __syncthreads();
    for (int i = t; i < 512; i += 256) {
        const int grow = bin * 512 + i;
        if (grow < N) {
            row_cnt[(size_t)rel * N + grow] = rc[i];
            row_beg[(size_t)rel * N + grow] = (int)(base + ro[i]);
        }
    }
    for (int i = t; i < n; i += 256) {
        const unsigned r = stage[i];
        const int pos = atomicAdd(&rcur[(r >> 16) & 511], 1);
        recs[base + pos] = r & 0xffffu;
    }
}

// ==================== LDS-staged dual-output GEMM ====================
// Wt tiles double-buffered in LDS (16 KB/tile both relations), T14 async split:
// issue next-tile global loads BEFORE the MFMA phase, ds_write after.
// Chunk XOR-swizzle (ch ^ (row&7)) makes the ds_read_b128 pattern conflict-free.
__global__ __launch_bounds__(256, 4) void gemm2_k(
    const float* __restrict__ X,
    const __hip_bfloat16* __restrict__ Wt0, const __hip_bfloat16* __restrict__ Wt1,
    const int* __restrict__ deg0, const int* __restrict__ deg1,
    __hip_bfloat16* __restrict__ Y0, __hip_bfloat16* __restrict__ Y1, int M) {
    __shared__ __hip_bfloat16 wlds[2][2][16][DDIM];   // [dbuf][rel][row][col] = 32 KB
    const int t = threadIdx.x;
    const int lane = t & 63, wid = t >> 6;
    const int c = lane & 15, kb = lane >> 4;
    const int rA = blockIdx.x * 128 + wid * 32 + c;
    const int rB = rA + 16;
    const bool vA = rA < M, vB = rB < M;
    const int rAc = vA ? rA : (M - 1), rBc = vB ? rB : (M - 1);

    // X fragments (f32 -> bf16, in registers for the whole kernel)
    s8v xfA[8], xfB[8];
    const float* xA = X + (size_t)rAc * DDIM;
    const float* xB = X + (size_t)rBc * DDIM;
    #pragma unroll
    for (int ks = 0; ks < 8; ++ks) {
        const int k0 = ks * 32 + kb * 8;
        const f4v a0 = *reinterpret_cast<const f4v*>(xA + k0);
        const f4v a1 = *reinterpret_cast<const f4v*>(xA + k0 + 4);
        const f4v b0 = *reinterpret_cast<const f4v*>(xB + k0);
        const f4v b1 = *reinterpret_cast<const f4v*>(xB + k0 + 4);
        union { s8v v; unsigned short u[8]; } fa, fb;
        #pragma unroll
        for (int j = 0; j < 4; ++j) {
            fa.u[j] = f2bf(a0[j]); fa.u[4 + j] = f2bf(a1[j]);
            fb.u[j] = f2bf(b0[j]); fb.u[4 + j] = f2bf(b1[j]);
        }
        xfA[ks] = fa.v; xfB[ks] = fb.v;
    }

    const int dA0 = deg0[rAc], dB0 = deg0[rBc], dA1 = deg1[rAc], dB1 = deg1[rBc];
    const float s0A = rsqrtf((float)(dA0 < 1 ? 1 : dA0));
    const float s0B = rsqrtf((float)(dB0 < 1 ? 1 : dB0));
    const float s1A = rsqrtf((float)(dA1 < 1 ? 1 : dA1));
    const float s1B = rsqrtf((float)(dB1 < 1 ? 1 : dB1));

    // thread t stages 4 x 16B chunks per tile: chunk q = t + j*256 over [0,1024)
    // q: rel = q>>9, row = (q>>5)&15, ch = q&31; LDS chunk = ch ^ (row&7)
    // prologue: stage tile 0 into buf 0
    {
        #pragma unroll
        for (int j = 0; j < 4; ++j) {
            const int q = t + j * 256;
            const int rel = q >> 9, rt = (q >> 5) & 15, ch = q & 31;
            const __hip_bfloat16* Wsrc = rel ? Wt1 : Wt0;
            const uint4 v = *reinterpret_cast<const uint4*>(Wsrc + (size_t)rt * DDIM + ch * 8);
            *reinterpret_cast<uint4*>(&wlds[0][rel][rt][(ch ^ (rt & 7)) * 8]) = v;
        }
    }

    #pragma unroll 2
    for (int nt = 0; nt < 16; ++nt) {
        __syncthreads();                       // staged tile nt visible
        // T14: issue next tile's global loads now, write to LDS after compute
        uint4 sv[4];
        if (nt + 1 < 16) {
            #pragma unroll
            for (int j = 0; j < 4; ++j) {
                const int q = t + j * 256;
                const int rel = q >> 9, rt = (q >> 5) & 15, ch = q & 31;
                const __hip_bfloat16* Wsrc = rel ? Wt1 : Wt0;
                sv[j] = *reinterpret_cast<const uint4*>(
                    Wsrc + (size_t)((nt + 1) * 16 + rt) * DDIM + ch * 8);
            }
        }

        // compute tile nt from LDS
        const int buf = nt & 1;
        f4v a00 = (f4v){0.f,0.f,0.f,0.f}, a01 = a00, a10 = a00, a11 = a00;
        #pragma unroll
        for (int ks = 0; ks < 8; ++ks) {
            const int chs = ((kb + 4 * ks) ^ (c & 7)) * 8;
            const s8v wf0 = *reinterpret_cast<const s8v*>(&wlds[buf][0][c][chs]);
            const s8v wf1 = *reinterpret_cast<const s8v*>(&wlds[buf][1][c][chs]);
            a00 = __builtin_amdgcn_mfma_f32_16x16x32_bf16(wf0, xfA[ks], a00, 0, 0, 0);
            a10 = __builtin_amdgcn_mfma_f32_16x16x32_bf16(wf0, xfB[ks], a10, 0, 0, 0);
            a01 = __builtin_amdgcn_mfma_f32_16x16x32_bf16(wf1, xfA[ks], a01, 0, 0, 0);
            a11 = __builtin_amdgcn_mfma_f32_16x16x32_bf16(wf1, xfB[ks], a11, 0, 0, 0);
        }
        const int col = nt * 16 + kb * 4;
        if (vA) {
            uint2 o0, o1;
            o0.x = pack2(a00[0] * s0A, a00[1] * s0A); o0.y = pack2(a00[2] * s0A, a00[3] * s0A);
            o1.x = pack2(a01[0] * s1A, a01[1] * s1A); o1.y = pack2(a01[2] * s1A, a01[3] * s1A);
            *reinterpret_cast<uint2*>(Y0 + (size_t)rA * DDIM + col) = o0;
            *reinterpret_cast<uint2*>(Y1 + (size_t)rA * DDIM + col) = o1;
        }
        if (vB) {
            uint2 o0, o1;
            o0.x = pack2(a10[0] * s0B, a10[1] * s0B); o0.y = pack2(a10[2] * s0B, a10[3] * s0B);
            o1.x = pack2(a11[0] * s1B, a11[1] * s1B); o1.y = pack2(a11[2] * s1B, a11[3] * s1B);
            *reinterpret_cast<uint2*>(Y0 + (size_t)rB * DDIM + col) = o0;
            *reinterpret_cast<uint2*>(Y1 + (size_t)rB * DDIM + col) = o1;
        }

        // late LDS write of tile nt+1 (other buffer; readers fenced by next barrier)
        if (nt + 1 < 16) {
            #pragma unroll
            for (int j = 0; j < 4; ++j) {
                const int q = t + j * 256;
                const int rel = q >> 9, rt = (q >> 5) & 15, ch = q & 31;
                *reinterpret_cast<uint4*>(&wlds[buf ^ 1][rel][rt][(ch ^ (rt & 7)) * 8]) = sv[j];
            }
        }
    }
}

// ---------------- LDS-staged single-output GEMM ----------------
__global__ __launch_bounds__(256, 4) void gemm1_k(
    const float* __restrict__ X, const __hip_bfloat16* __restrict__ Wt0,
    const int* __restrict__ deg0, __hip_bfloat16* __restrict__ Y0, int M) {
    __shared__ __hip_bfloat16 wlds[2][16][DDIM];   // 16 KB
    const int t = threadIdx.x;
    const int lane = t & 63, wid = t >> 6;
    const int c = lane & 15, kb = lane >> 4;
    const int rA = blockIdx.x * 128 + wid * 32 + c;
    const int rB = rA + 16;
    const bool vA = rA < M, vB = rB < M;
    const int rAc = vA ? rA : (M - 1), rBc = vB ? rB : (M - 1);

    s8v xfA[8], xfB[8];
    const float* xA = X + (size_t)rAc * DDIM;
    const float* xB = X + (size_t)rBc * DDIM;
    #pragma unroll
    for (int ks = 0; ks < 8; ++ks) {
        const int k0 = ks * 32 + kb * 8;
        const f4v a0 = *reinterpret_cast<const f4v*>(xA + k0);
        const f4v a1 = *reinterpret_cast<const f4v*>(xA + k0 + 4);
        const f4v b0 = *reinterpret_cast<const f4v*>(xB + k0);
        const f4v b1 = *reinterpret_cast<const f4v*>(xB + k0 + 4);
        union { s8v v; unsigned short u[8]; } fa, fb;
        #pragma unroll
        for (int j = 0; j < 4; ++j) {
            fa.u[j] = f2bf(a0[j]); fa.u[4 + j] = f2bf(a1[j]);
            fb.u[j] = f2bf(b0[j]); fb.u[4 + j] = f2bf(b1[j]);
        }
        xfA[ks] = fa.v; xfB[ks] = fb.v;
    }
    const int dA0 = deg0[rAc], dB0 = deg0[rBc];
    const float s0A = rsqrtf((float)(dA0 < 1 ? 1 : dA0));
    const float s0B = rsqrtf((float)(dB0 < 1 ? 1 : dB0));

    // thread t stages 2 x 16B chunks: q = t + j*256 over [0,512)
    {
        #pragma unroll
        for (int j = 0; j < 2; ++j) {
            const int q = t + j * 256;
            const int rt = (q >> 5) & 15, ch = q & 31;
            const uint4 v = *reinterpret_cast<const uint4*>(Wt0 + (size_t)rt * DDIM + ch * 8);
            *reinterpret_cast<uint4*>(&wlds[0][rt][(ch ^ (rt & 7)) * 8]) = v;
        }
    }

    #pragma unroll 2
    for (int nt = 0; nt < 16; ++nt) {
        __syncthreads();
        uint4 sv[2];
        if (nt + 1 < 16) {
            #pragma unroll
            for (int j = 0; j < 2; ++j) {
                const int q = t + j * 256;
                const int rt = (q >> 5) & 15, ch = q & 31;
                sv[j] = *reinterpret_cast<const uint4*>(
                    Wt0 + (size_t)((nt + 1) * 16 + rt) * DDIM + ch * 8);
            }
        }

        const int buf = nt & 1;
        f4v a00 = (f4v){0.f,0.f,0.f,0.f}, a10 = a00;
        #pragma unroll
        for (int ks = 0; ks < 8; ++ks) {
            const int chs = ((kb + 4 * ks) ^ (c & 7)) * 8;
            const s8v wf0 = *reinterpret_cast<const s8v*>(&wlds[buf][c][chs]);
            a00 = __builtin_amdgcn_mfma_f32_16x16x32_bf16(wf0, xfA[ks], a00, 0, 0, 0);
            a10 = __builtin_amdgcn_mfma_f32_16x16x32_bf16(wf0, xfB[ks], a10, 0, 0, 0);
        }
        const int col = nt * 16 + kb * 4;
        if (vA) {
            uint2 o;
            o.x = pack2(a00[0] * s0A, a00[1] * s0A); o.y = pack2(a00[2] * s0A, a00[3] * s0A);
            *reinterpret_cast<uint2*>(Y0 + (size_t)rA * DDIM + col) = o;
        }
        if (vB) {
            uint2 o;
            o.x = pack2(a10[0] * s0B, a10[1] * s0B); o.y = pack2(a10[2] * s0B, a10[3] * s0B);
            *reinterpret_cast<uint2*>(Y0 + (size_t)rB * DDIM + col) = o;
        }

        if (nt + 1 < 16) {
            #pragma unroll
            for (int j = 0; j < 2; ++j) {
                const int q = t + j * 256;
                const int rt = (q >> 5) & 15, ch = q & 31;
                *reinterpret_cast<uint4*>(&wlds[buf ^ 1][rt][(ch ^ (rt & 7)) * 8]) = sv[j];
            }
        }
    }
}

// ---------------- gather helpers (round-9 proven form) ----------------
__device__ __forceinline__ void addv(f4v& a, uint2 v) {
    a[0] += bf2f(v.x & 0xffffu);
    a[1] += bf2f(v.x >> 16);
    a[2] += bf2f(v.y & 0xffffu);
    a[3] += bf2f(v.y >> 16);
}

__device__ __forceinline__ f4v segsum(const unsigned* __restrict__ recs, int beg, int n,
                                      const __hip_bfloat16* __restrict__ Y, int lane) {
    f4v a = (f4v){0.f, 0.f, 0.f, 0.f};
    for (int j0 = 0; j0 < n; j0 += 64) {
        const int chunk = min(64, n - j0);
        unsigned rv = 0;
        if (lane < chunk) rv = recs[beg + j0 + lane];
        int t = 0;
        for (; t + 8 <= chunk; t += 8) {
            uint2 v[8];
            #pragma unroll
            for (int i = 0; i < 8; ++i) {
                const int s = (int)(__shfl(rv, t + i) & 0xffffu);
                v[i] = reinterpret_cast<const uint2*>(Y + (size_t)s * DDIM)[lane];
            }
            #pragma unroll
            for (int i = 0; i < 8; ++i) addv(a, v[i]);
        }
        if (t + 4 <= chunk) {
            uint2 v[4];
            #pragma unroll
            for (int i = 0; i < 4; ++i) {
                const int s = (int)(__shfl(rv, t + i) & 0xffffu);
                v[i] = reinterpret_cast<const uint2*>(Y + (size_t)s * DDIM)[lane];
            }
            #pragma unroll
            for (int i = 0; i < 4; ++i) addv(a, v[i]);
            t += 4;
        }
        for (; t < chunk; ++t) {
            const int s = (int)(__shfl(rv, t) & 0xffffu);
            addv(a, reinterpret_cast<const uint2*>(Y + (size_t)s * DDIM)[lane]);
        }
    }
    return a;
}

// ---------------- gather (+ optional 2nd relation) + LayerNorm + bias + ReLU ----------------
__global__ __launch_bounds__(256, 4) void gather_ln_k(
    const unsigned* __restrict__ recs,
    const int* __restrict__ beg0, const int* __restrict__ cnt0,
    const __hip_bfloat16* __restrict__ Y0,
    const int* __restrict__ beg1, const int* __restrict__ cnt1,
    const __hip_bfloat16* __restrict__ Y1,          // beg1 == null -> single relation
    const float* __restrict__ gamma, const float* __restrict__ beta,
    const float* __restrict__ bias, float* __restrict__ out, int n_dst) {
    const int lane = threadIdx.x & 63, wid = threadIdx.x >> 6;
    const int row = blockIdx.x * 4 + wid;
    if (row >= n_dst) return;

    const int n0 = cnt0[row];
    f4v a = segsum(recs, beg0[row], n0, Y0, lane);
    a *= rsqrtf((float)(n0 < 1 ? 1 : n0));
    if (beg1 != nullptr) {
        const int n1 = cnt1[row];
        f4v a1 = segsum(recs, beg1[row], n1, Y1, lane);
        a += a1 * rsqrtf((float)(n1 < 1 ? 1 : n1));
    }

    float s1 = a[0] + a[1] + a[2] + a[3];
    float s2 = a[0]*a[0] + a[1]*a[1] + a[2]*a[2] + a[3]*a[3];
    #pragma unroll
    for (int off = 1; off < 64; off <<= 1) {
        s1 += __shfl_xor(s1, off);
        s2 += __shfl_xor(s2, off);
    }
    const float mu = s1 * (1.f / 256.f);
    float var = s2 * (1.f / 256.f) - mu * mu;
    var = fmaxf(var, 0.f);
    const float rs = rsqrtf(var + 1e-5f);

    const f4v g  = reinterpret_cast<const f4v*>(gamma)[lane];
    const f4v be = reinterpret_cast<const f4v*>(beta)[lane];
    const f4v bb = reinterpret_cast<const f4v*>(bias)[lane];
    f4v o;
    #pragma unroll
    for (int j = 0; j < 4; ++j) {
        float v = (a[j] - mu) * rs * g[j] + be[j] + bb[j];
        o[j] = fmaxf(v, 0.f);
    }
    reinterpret_cast<f4v*>(out + (size_t)row * DDIM)[lane] = o;
}

extern "C" void kernel_launch(void* const* d_in, const int* in_sizes, int n_in,
                              void* d_out, int out_size, void* d_ws, size_t ws_size,
                              hipStream_t stream) {
    const float* x_cell     = (const float*)d_in[0];
    const float* x_gene     = (const float*)d_in[1];
    const float* W_cg       = (const float*)d_in[2];
    const float* W_gc       = (const float*)d_in[3];
    const float* W_gg       = (const float*)d_in[4];
    const float* gamma_cell = (const float*)d_in[5];
    const float* beta_cell  = (const float*)d_in[6];
    const float* gamma_gene = (const float*)d_in[7];
    const float* beta_gene  = (const float*)d_in[8];
    const float* b_cell     = (const float*)d_in[9];
    const float* b_gene     = (const float*)d_in[10];
    const int* src_cg = (const int*)d_in[11];
    const int* dst_cg = (const int*)d_in[12];
    const int* src_gc = (const int*)d_in[13];
    const int* dst_gc = (const int*)d_in[14];
    const int* src_gg = (const int*)d_in[15];
    const int* dst_gg = (const int*)d_in[16];

    const int N = in_sizes[0] / DDIM;        // 50000
    const int E = in_sizes[11];              // 800000
    const int ncb = (N + 511) >> 9;          // 98 used coarse bins

    // ---- workspace layout (~47 MB) ----
    char* wsb = (char*)d_ws;
    size_t off = 0;
    __hip_bfloat16* Y_gc = (__hip_bfloat16*)(wsb + off); off += (size_t)N * DDIM * 2;           // 25.6 MB
    unsigned* recs = (unsigned*)(wsb + off);             off += (size_t)3 * NCPAD * CCAP * 4;   // 14.2 MB
    int* row_beg = (int*)(wsb + off);                    off += (size_t)3 * N * 4;              // 600 KB
    int* row_cnt = (int*)(wsb + off);                    off += (size_t)3 * N * 4;              // 600 KB
    int* cs      = (int*)(wsb + off);                    off += (size_t)3 * N * 4;              // 600 KB
    const size_t zeroOff = off;
    int* cs_shard = (int*)(wsb + off);                   off += (size_t)NSHARD * 3 * N * 4;     // 4.8 MB
    int* gcur     = (int*)(wsb + off);                   off += (size_t)3 * NCPAD * 4;          // 1.5 KB
    const size_t zeroBytes = off - zeroOff;
    __hip_bfloat16* Wt_gc = (__hip_bfloat16*)(wsb + off); off += (size_t)DDIM * DDIM * 2;
    __hip_bfloat16* Wt_cg = (__hip_bfloat16*)(wsb + off); off += (size_t)DDIM * DDIM * 2;
    __hip_bfloat16* Wt_gg = (__hip_bfloat16*)(wsb + off);

    int* cs_gc = cs, *cs_cg = cs + N, *cs_gg = cs + 2 * N;
    int* beg_gc = row_beg, *beg_cg = row_beg + N, *beg_gg = row_beg + 2 * N;
    int* cnt_gc = row_cnt, *cnt_cg = row_cnt + N, *cnt_gg = row_cnt + 2 * N;

    // Y_cg, Y_gg live in the d_out cell-half; consumed by the gene gather before
    // the cell gather overwrites that region with the final cell output.
    float* out_cell = (float*)d_out;
    float* out_gene = out_cell + (size_t)N * DDIM;
    __hip_bfloat16* Y_cg = (__hip_bfloat16*)d_out;
    __hip_bfloat16* Y_gg = Y_cg + (size_t)N * DDIM;

    const int binBlocks  = (E + T1 - 1) / T1;
    const int gemmBlocks = (N + 127) / 128;
    const int gatherBlocks = (N + 3) / 4;

    transpose3_k<<<dim3(DDIM, 3), DDIM, 0, stream>>>(W_gc, W_cg, W_gg, Wt_gc, Wt_cg, Wt_gg);
    hipMemsetAsync(wsb + zeroOff, 0, zeroBytes, stream);

    // relations: 0=gc, 1=cg, 2=gg
    bin1_k<<<dim3(binBlocks, 3), 256, 0, stream>>>(src_gc, dst_gc, src_cg, dst_cg,
                                                   src_gg, dst_gg, cs_shard, gcur, recs, N, E);
    reduce_cs_k<<<(3 * N + 255) / 256, 256, 0, stream>>>(cs_shard, cs, 3 * N);
    sort_k<<<3 * ncb, 256, 0, stream>>>(recs, gcur, row_beg, row_cnt, N, ncb);

    gemm2_k<<<gemmBlocks, 256, 0, stream>>>(x_gene, Wt_gc, Wt_gg, cs_gc, cs_gg,
                                            Y_gc, Y_gg, N);
    gemm1_k<<<gemmBlocks, 256, 0, stream>>>(x_cell, Wt_cg, cs_cg, Y_cg, N);

    // gene: cg + gg fused gather + LN
    gather_ln_k<<<gatherBlocks, 256, 0, stream>>>(recs, beg_cg, cnt_cg, Y_cg,
                                                  beg_gg, cnt_gg, Y_gg,
                                                  gamma_gene, beta_gene, b_gene, out_gene, N);
    // cell: gc gather + LN (overwrites Y_cg/Y_gg region)
    gather_ln_k<<<gatherBlocks, 256, 0, stream>>>(recs, beg_gc, cnt_gc, Y_gc,
                                                  nullptr, nullptr, nullptr,
                                                  gamma_cell, beta_cell, b_cell, out_cell, N);
}

// Round 14
// 395.555 us; speedup vs baseline: 1.6704x; 1.0237x over previous
//
#include <hip/hip_runtime.h>
#include <hip/hip_bf16.h>
#include <stdint.h>

#define DDIM 256
#define NSHARD 8          // shards for deg_out atomics
#define T1 4096           // edges per bin1 block
#define NCPAD 128         // padded coarse-bin count (dst>>9, 512 rows/bin)
#define CCAP 9216         // record capacity per (rel, coarse bin); mean 8192, +11 sigma

typedef short s8v __attribute__((ext_vector_type(8)));
typedef float f4v __attribute__((ext_vector_type(4)));

__device__ __forceinline__ float bf2f(unsigned u) { return __uint_as_float(u << 16); }
__device__ __forceinline__ unsigned short f2bf(float f) {
    __hip_bfloat16 h = __float2bfloat16(f);
    return *reinterpret_cast<unsigned short*>(&h);
}
__device__ __forceinline__ unsigned pack2(float a, float b) {
    return (unsigned)f2bf(a) | ((unsigned)f2bf(b) << 16);
}

// ---------------- fused W transpose + cast: T[n][k] = bf16(W[k][n]) ----------------
__global__ void transpose3_k(const float* __restrict__ W0, const float* __restrict__ W1,
                             const float* __restrict__ W2, __hip_bfloat16* __restrict__ T0,
                             __hip_bfloat16* __restrict__ T1v, __hip_bfloat16* __restrict__ T2) {
    const float* W = (blockIdx.y == 0) ? W0 : (blockIdx.y == 1) ? W1 : W2;
    __hip_bfloat16* T = (blockIdx.y == 0) ? T0 : (blockIdx.y == 1) ? T1v : T2;
    T[blockIdx.x * DDIM + threadIdx.x] = __float2bfloat16(W[threadIdx.x * DDIM + blockIdx.x]);
}

// ---------------- pass 1: LDS-staged coarse binning (dense segment writes) ----------------
// record = src | (dst&511)<<16 | bin<<25 ; bin = dst>>9.
__global__ __launch_bounds__(256) void bin1_k(
    const int* __restrict__ s0, const int* __restrict__ d0,
    const int* __restrict__ s1, const int* __restrict__ d1,
    const int* __restrict__ s2, const int* __restrict__ d2,
    int* __restrict__ cs_shard,      // [NSHARD][3][N]
    int* __restrict__ gcur,          // [3][NCPAD]
    unsigned* __restrict__ recs,     // [3][NCPAD][CCAP]
    int N, int E) {
    __shared__ unsigned stage[T1];           // 16 KB
    __shared__ int hcnt[NCPAD], hoff[NCPAD], lbase[NCPAD], lcur[NCPAD];
    const int t = threadIdx.x;
    const int rel = blockIdx.y;
    const int* s = (rel == 0) ? s0 : (rel == 1) ? s1 : s2;
    const int* d = (rel == 0) ? d0 : (rel == 1) ? d1 : d2;
    const int e0 = blockIdx.x * T1;
    const int n = min(T1, E - e0);
    int* csb = cs_shard + ((size_t)(blockIdx.x & (NSHARD - 1)) * 3 + rel) * N;

    if (t < NCPAD) { hcnt[t] = 0; lcur[t] = 0; }
    __syncthreads();

    int ssr[T1 / 256], ddr[T1 / 256];
    #pragma unroll
    for (int k = 0; k < T1 / 256; ++k) {
        const int li = k * 256 + t;
        const bool v = li < n;
        ssr[k] = v ? s[e0 + li] : -1;
        ddr[k] = v ? d[e0 + li] : -1;
        if (v) {
            atomicAdd(&hcnt[ddr[k] >> 9], 1);
            atomicAdd(&csb[ssr[k]], 1);
        }
    }
    __syncthreads();

    if (t < 64) {
        const int a0 = hcnt[2 * t], a1 = hcnt[2 * t + 1];
        const int sum = a0 + a1;
        int incl = sum;
        #pragma unroll
        for (int off = 1; off < 64; off <<= 1) {
            const int u = __shfl_up(incl, off);
            if (t >= off) incl += u;
        }
        const int excl = incl - sum;
        hoff[2 * t] = excl;
        hoff[2 * t + 1] = excl + a0;
    }
    __syncthreads();
    if (t < NCPAD) lbase[t] = atomicAdd(&gcur[rel * NCPAD + t], hcnt[t]);
    __syncthreads();

    #pragma unroll
    for (int k = 0; k < T1 / 256; ++k) {
        if (ddr[k] >= 0) {
            const int b = ddr[k] >> 9;
            const int p = atomicAdd(&lcur[b], 1);
            stage[hoff[b] + p] = (unsigned)ssr[k] | ((unsigned)(ddr[k] & 511) << 16)
                                 | ((unsigned)b << 25);
        }
    }
    __syncthreads();

    for (int i = t; i < n; i += 256) {
        const unsigned r = stage[i];
        const int b = (int)(r >> 25);
        const int pos = lbase[b] + (i - hoff[b]);
        if (pos < CCAP)
            recs[((size_t)rel * NCPAD + b) * CCAP + pos] = r & 0x1FFFFFFu;
    }
}

// ---------------- deg_out from shards, inline ----------------
__device__ __forceinline__ int deg_sum(const int* __restrict__ cs_shard, int rel, int r, int N) {
    int v = 0;
    #pragma unroll
    for (int s = 0; s < NSHARD; ++s) v += cs_shard[((size_t)s * 3 + rel) * N + r];
    return v;
}

// ==================== mid_k bodies (union LDS, 32 KB) ====================

// sort: per-coarse-bin counting sort by dst row; emits u16 src records.
// LDS use: u16 stage[CCAP] (18 KB) + 3 x int[512] (6 KB) = 24.5 KB of the union.
__device__ void sort_body(int sb, unsigned char* smem,
                          const unsigned* __restrict__ recs32,
                          unsigned short* __restrict__ recs16,
                          const int* __restrict__ gcur,
                          int* __restrict__ row_beg, int* __restrict__ row_cnt,
                          int N, int ncb) {
    unsigned short* stage = (unsigned short*)smem;                 // [CCAP]
    int* rc   = (int*)(smem + 18432);
    int* ro   = (int*)(smem + 20480);
    int* rcur = (int*)(smem + 22528);
    const int t = threadIdx.x;
    const int rel = sb / ncb, bin = sb % ncb;
    const size_t base = ((size_t)rel * NCPAD + bin) * CCAP;
    const int n = min(gcur[rel * NCPAD + bin], CCAP);

    for (int i = t; i < 512; i += 256) rc[i] = 0;
    __syncthreads();
    for (int i = t; i < n; i += 256)
        atomicAdd(&rc[(recs32[base + i] >> 16) & 511], 1);
    __syncthreads();
    if (t < 64) {
        int v[8], p[8], sum = 0;
        #pragma unroll
        for (int j = 0; j < 8; ++j) { v[j] = rc[t * 8 + j]; p[j] = sum; sum += v[j]; }
        int incl = sum;
        #pragma unroll
        for (int off = 1; off < 64; off <<= 1) {
            const int u = __shfl_up(incl, off);
            if (t >= off) incl += u;
        }
        const int excl = incl - sum;
        #pragma unroll
        for (int j = 0; j < 8; ++j) { ro[t * 8 + j] = excl + p[j]; rcur[t * 8 + j] = excl + p[j]; }
    }
    __syncthreads();
    for (int i = t; i < 512; i += 256) {
        const int grow = bin * 512 + i;
        if (grow < N) {
            row_cnt[(size_t)rel * N + grow] = rc[i];
            row_beg[(size_t)rel * N + grow] = (int)(base + ro[i]);
        }
    }
    // scatter into LDS (re-read recs32: 36 KB region, L2-hot)
    for (int i = t; i < n; i += 256) {
        const unsigned r = recs32[base + i];
        const int pos = atomicAdd(&rcur[(r >> 16) & 511], 1);
        stage[pos] = (unsigned short)(r & 0xffffu);
    }
    __syncthreads();
    for (int i = t; i < n; i += 256)
        recs16[base + i] = stage[i];
}

// dual-output GEMM, LDS double-buffered Wt (uses the full 32 KB union)
__device__ void gemm2_body(int gb, unsigned char* smem, const float* __restrict__ X,
                           const __hip_bfloat16* __restrict__ Wt0,
                           const __hip_bfloat16* __restrict__ Wt1,
                           const int* __restrict__ cs_shard, int rel0, int rel1,
                           __hip_bfloat16* __restrict__ Y0, __hip_bfloat16* __restrict__ Y1,
                           int M, int N) {
    typedef __hip_bfloat16 (*lds_t)[2][16][DDIM];
    lds_t wlds = (lds_t)smem;                       // [dbuf][rel][row][col]
    const int t = threadIdx.x;
    const int lane = t & 63, wid = t >> 6;
    const int c = lane & 15, kb = lane >> 4;
    const int rA = gb * 128 + wid * 32 + c;
    const int rB = rA + 16;
    const bool vA = rA < M, vB = rB < M;
    const int rAc = vA ? rA : (M - 1), rBc = vB ? rB : (M - 1);

    s8v xfA[8], xfB[8];
    const float* xA = X + (size_t)rAc * DDIM;
    const float* xB = X + (size_t)rBc * DDIM;
    #pragma unroll
    for (int ks = 0; ks < 8; ++ks) {
        const int k0 = ks * 32 + kb * 8;
        const f4v a0 = *reinterpret_cast<const f4v*>(xA + k0);
        const f4v a1 = *reinterpret_cast<const f4v*>(xA + k0 + 4);
        const f4v b0 = *reinterpret_cast<const f4v*>(xB + k0);
        const f4v b1 = *reinterpret_cast<const f4v*>(xB + k0 + 4);
        union { s8v v; unsigned short u[8]; } fa, fb;
        #pragma unroll
        for (int j = 0; j < 4; ++j) {
            fa.u[j] = f2bf(a0[j]); fa.u[4 + j] = f2bf(a1[j]);
            fb.u[j] = f2bf(b0[j]); fb.u[4 + j] = f2bf(b1[j]);
        }
        xfA[ks] = fa.v; xfB[ks] = fb.v;
    }

    const int dA0 = deg_sum(cs_shard, rel0, rAc, N), dB0 = deg_sum(cs_shard, rel0, rBc, N);
    const int dA1 = deg_sum(cs_shard, rel1, rAc, N), dB1 = deg_sum(cs_shard, rel1, rBc, N);
    const float s0A = rsqrtf((float)(dA0 < 1 ? 1 : dA0));
    const float s0B = rsqrtf((float)(dB0 < 1 ? 1 : dB0));
    const float s1A = rsqrtf((float)(dA1 < 1 ? 1 : dA1));
    const float s1B = rsqrtf((float)(dB1 < 1 ? 1 : dB1));

    // prologue: stage tile 0 into buf 0 (4 x 16B chunks/thread; chunk swizzle ch^(row&7))
    {
        #pragma unroll
        for (int j = 0; j < 4; ++j) {
            const int q = t + j * 256;
            const int rel = q >> 9, rt = (q >> 5) & 15, ch = q & 31;
            const __hip_bfloat16* Wsrc = rel ? Wt1 : Wt0;
            const uint4 v = *reinterpret_cast<const uint4*>(Wsrc + (size_t)rt * DDIM + ch * 8);
            *reinterpret_cast<uint4*>(&(*wlds)[0 * 2 + rel][rt][(ch ^ (rt & 7)) * 8]) = v;
        }
    }

    #pragma unroll 2
    for (int nt = 0; nt < 16; ++nt) {
        __syncthreads();
        uint4 sv[4];
        if (nt + 1 < 16) {
            #pragma unroll
            for (int j = 0; j < 4; ++j) {
                const int q = t + j * 256;
                const int rel = q >> 9, rt = (q >> 5) & 15, ch = q & 31;
                const __hip_bfloat16* Wsrc = rel ? Wt1 : Wt0;
                sv[j] = *reinterpret_cast<const uint4*>(
                    Wsrc + (size_t)((nt + 1) * 16 + rt) * DDIM + ch * 8);
            }
        }

        const int buf = nt & 1;
        f4v a00 = (f4v){0.f,0.f,0.f,0.f}, a01 = a00, a10 = a00, a11 = a00;
        #pragma unroll
        for (int ks = 0; ks < 8; ++ks) {
            const int chs = ((kb + 4 * ks) ^ (c & 7)) * 8;
            const s8v wf0 = *reinterpret_cast<const s8v*>(&(*wlds)[buf * 2 + 0][c][chs]);
            const s8v wf1 = *reinterpret_cast<const s8v*>(&(*wlds)[buf * 2 + 1][c][chs]);
            a00 = __builtin_amdgcn_mfma_f32_16x16x32_bf16(wf0, xfA[ks], a00, 0, 0, 0);
            a10 = __builtin_amdgcn_mfma_f32_16x16x32_bf16(wf0, xfB[ks], a10, 0, 0, 0);
            a01 = __builtin_amdgcn_mfma_f32_16x16x32_bf16(wf1, xfA[ks], a01, 0, 0, 0);
            a11 = __builtin_amdgcn_mfma_f32_16x16x32_bf16(wf1, xfB[ks], a11, 0, 0, 0);
        }
        const int col = nt * 16 + kb * 4;
        if (vA) {
            uint2 o0, o1;
            o0.x = pack2(a00[0] * s0A, a00[1] * s0A); o0.y = pack2(a00[2] * s0A, a00[3] * s0A);
            o1.x = pack2(a01[0] * s1A, a01[1] * s1A); o1.y = pack2(a01[2] * s1A, a01[3] * s1A);
            *reinterpret_cast<uint2*>(Y0 + (size_t)rA * DDIM + col) = o0;
            *reinterpret_cast<uint2*>(Y1 + (size_t)rA * DDIM + col) = o1;
        }
        if (vB) {
            uint2 o0, o1;
            o0.x = pack2(a10[0] * s0B, a10[1] * s0B); o0.y = pack2(a10[2] * s0B, a10[3] * s0B);
            o1.x = pack2(a11[0] * s1B, a11[1] * s1B); o1.y = pack2(a11[2] * s1B, a11[3] * s1B);
            *reinterpret_cast<uint2*>(Y0 + (size_t)rB * DDIM + col) = o0;
            *reinterpret_cast<uint2*>(Y1 + (size_t)rB * DDIM + col) = o1;
        }

        if (nt + 1 < 16) {
            #pragma unroll
            for (int j = 0; j < 4; ++j) {
                const int q = t + j * 256;
                const int rel = q >> 9, rt = (q >> 5) & 15, ch = q & 31;
                *reinterpret_cast<uint4*>(&(*wlds)[(buf ^ 1) * 2 + rel][rt][(ch ^ (rt & 7)) * 8]) = sv[j];
            }
        }
    }
}

// single-output GEMM (uses 16 KB of the union: two 8 KB tile buffers)
__device__ void gemm1_body(int gb, unsigned char* smem, const float* __restrict__ X,
                           const __hip_bfloat16* __restrict__ Wt0,
                           const int* __restrict__ cs_shard, int rel0,
                           __hip_bfloat16* __restrict__ Y0, int M, int N) {
    typedef __hip_bfloat16 (*lds_t)[16][DDIM];
    lds_t wlds = (lds_t)smem;                       // [dbuf][row][col]
    const int t = threadIdx.x;
    const int lane = t & 63, wid = t >> 6;
    const int c = lane & 15, kb = lane >> 4;
    const int rA = gb * 128 + wid * 32 + c;
    const int rB = rA + 16;
    const bool vA = rA < M, vB = rB < M;
    const int rAc = vA ? rA : (M - 1), rBc = vB ? rB : (M - 1);

    s8v xfA[8], xfB[8];
    const float* xA = X + (size_t)rAc * DDIM;
    const float* xB = X + (size_t)rBc * DDIM;
    #pragma unroll
    for (int ks = 0; ks < 8; ++ks) {
        const int k0 = ks * 32 + kb * 8;
        const f4v a0 = *reinterpret_cast<const f4v*>(xA + k0);
        const f4v a1 = *reinterpret_cast<const f4v*>(xA + k0 + 4);
        const f4v b0 = *reinterpret_cast<const f4v*>(xB + k0);
        const f4v b1 = *reinterpret_cast<const f4v*>(xB + k0 + 4);
        union { s8v v; unsigned short u[8]; } fa, fb;
        #pragma unroll
        for (int j = 0; j < 4; ++j) {
            fa.u[j] = f2bf(a0[j]); fa.u[4 + j] = f2bf(a1[j]);
            fb.u[j] = f2bf(b0[j]); fb.u[4 + j] = f2bf(b1[j]);
        }
        xfA[ks] = fa.v; xfB[ks] = fb.v;
    }
    const int dA0 = deg_sum(cs_shard, rel0, rAc, N), dB0 = deg_sum(cs_shard, rel0, rBc, N);
    const float s0A = rsqrtf((float)(dA0 < 1 ? 1 : dA0));
    const float s0B = rsqrtf((float)(dB0 < 1 ? 1 : dB0));

    {
        #pragma unroll
        for (int j = 0; j < 2; ++j) {
            const int q = t + j * 256;
            const int rt = (q >> 5) & 15, ch = q & 31;
            const uint4 v = *reinterpret_cast<const uint4*>(Wt0 + (size_t)rt * DDIM + ch * 8);
            *reinterpret_cast<uint4*>(&(*wlds)[0 * 16 + rt][(ch ^ (rt & 7)) * 8]) = v;
        }
    }

    #pragma unroll 2
    for (int nt = 0; nt < 16; ++nt) {
        __syncthreads();
        uint4 sv[2];
        if (nt + 1 < 16) {
            #pragma unroll
            for (int j = 0; j < 2; ++j) {
                const int q = t + j * 256;
                const int rt = (q >> 5) & 15, ch = q & 31;
                sv[j] = *reinterpret_cast<const uint4*>(
                    Wt0 + (size_t)((nt + 1) * 16 + rt) * DDIM + ch * 8);
            }
        }

        const int buf = nt & 1;
        f4v a00 = (f4v){0.f,0.f,0.f,0.f}, a10 = a00;
        #pragma unroll
        for (int ks = 0; ks < 8; ++ks) {
            const int chs = ((kb + 4 * ks) ^ (c & 7)) * 8;
            const s8v wf0 = *reinterpret_cast<const s8v*>(&(*wlds)[buf * 16 + c][chs]);
            a00 = __builtin_amdgcn_mfma_f32_16x16x32_bf16(wf0, xfA[ks], a00, 0, 0, 0);
            a10 = __builtin_amdgcn_mfma_f32_16x16x32_bf16(wf0, xfB[ks], a10, 0, 0, 0);
        }
        const int col = nt * 16 + kb * 4;
        if (vA) {
            uint2 o;
            o.x = pack2(a00[0] * s0A, a00[1] * s0A); o.y = pack2(a00[2] * s0A, a00[3] * s0A);
            *reinterpret_cast<uint2*>(Y0 + (size_t)rA * DDIM + col) = o;
        }
        if (vB) {
            uint2 o;
            o.x = pack2(a10[0] * s0B, a10[1] * s0B); o.y = pack2(a10[2] * s0B, a10[3] * s0B);
            *reinterpret_cast<uint2*>(Y0 + (size_t)rB * DDIM + col) = o;
        }

        if (nt + 1 < 16) {
            #pragma unroll
            for (int j = 0; j < 2; ++j) {
                const int q = t + j * 256;
                const int rt = (q >> 5) & 15, ch = q & 31;
                *reinterpret_cast<uint4*>(&(*wlds)[(buf ^ 1) * 16 + rt][(ch ^ (rt & 7)) * 8]) = sv[j];
            }
        }
    }
}

// ---------------- mid: gemm2 + gemm1 + sort in one dispatch (32 KB union LDS) ----------------
__global__ __launch_bounds__(256, 4) void mid_k(
    const unsigned* __restrict__ recs32, unsigned short* __restrict__ recs16,
    const int* __restrict__ gcur,
    int* __restrict__ row_beg, int* __restrict__ row_cnt,
    const float* __restrict__ x_gene, const float* __restrict__ x_cell,
    const __hip_bfloat16* __restrict__ Wt_gc, const __hip_bfloat16* __restrict__ Wt_gg,
    const __hip_bfloat16* __restrict__ Wt_cg,
    const int* __restrict__ cs_shard,
    __hip_bfloat16* __restrict__ Y_gc, __hip_bfloat16* __restrict__ Y_gg,
    __hip_bfloat16* __restrict__ Y_cg,
    int N, int ncb, int gemmBlocks) {
    __shared__ uint4 smem4[2048];                  // 32 KB union
    unsigned char* smem = (unsigned char*)smem4;
    const int bid = blockIdx.x;
    if (bid < gemmBlocks) {
        gemm2_body(bid, smem, x_gene, Wt_gc, Wt_gg, cs_shard, 0, 2, Y_gc, Y_gg, N, N);
    } else if (bid < 2 * gemmBlocks) {
        gemm1_body(bid - gemmBlocks, smem, x_cell, Wt_cg, cs_shard, 1, Y_cg, N, N);
    } else {
        sort_body(bid - 2 * gemmBlocks, smem, recs32, recs16, gcur,
                  row_beg, row_cnt, N, ncb);
    }
}

// ---------------- gather helpers (u16 records) ----------------
__device__ __forceinline__ void addv(f4v& a, uint2 v) {
    a[0] += bf2f(v.x & 0xffffu);
    a[1] += bf2f(v.x >> 16);
    a[2] += bf2f(v.y & 0xffffu);
    a[3] += bf2f(v.y >> 16);
}

__device__ __forceinline__ f4v segsum(const unsigned short* __restrict__ recs, int beg, int n,
                                      const __hip_bfloat16* __restrict__ Y, int lane) {
    f4v a = (f4v){0.f, 0.f, 0.f, 0.f};
    for (int j0 = 0; j0 < n; j0 += 64) {
        const int chunk = min(64, n - j0);
        unsigned rv = 0;
        if (lane < chunk) rv = recs[beg + j0 + lane];
        int t = 0;
        for (; t + 8 <= chunk; t += 8) {
            uint2 v[8];
            #pragma unroll
            for (int i = 0; i < 8; ++i) {
                const int s = (int)__shfl(rv, t + i);
                v[i] = reinterpret_cast<const uint2*>(Y + (size_t)s * DDIM)[lane];
            }
            #pragma unroll
            for (int i = 0; i < 8; ++i) addv(a, v[i]);
        }
        if (t + 4 <= chunk) {
            uint2 v[4];
            #pragma unroll
            for (int i = 0; i < 4; ++i) {
                const int s = (int)__shfl(rv, t + i);
                v[i] = reinterpret_cast<const uint2*>(Y + (size_t)s * DDIM)[lane];
            }
            #pragma unroll
            for (int i = 0; i < 4; ++i) addv(a, v[i]);
            t += 4;
        }
        for (; t < chunk; ++t) {
            const int s = (int)__shfl(rv, t);
            addv(a, reinterpret_cast<const uint2*>(Y + (size_t)s * DDIM)[lane]);
        }
    }
    return a;
}

// ---------------- gather (+ optional 2nd relation) + LayerNorm + bias + ReLU ----------------
__global__ __launch_bounds__(256, 4) void gather_ln_k(
    const unsigned short* __restrict__ recs,
    const int* __restrict__ beg0, const int* __restrict__ cnt0,
    const __hip_bfloat16* __restrict__ Y0,
    const int* __restrict__ beg1, const int* __restrict__ cnt1,
    const __hip_bfloat16* __restrict__ Y1,          // beg1 == null -> single relation
    const float* __restrict__ gamma, const float* __restrict__ beta,
    const float* __restrict__ bias, float* __restrict__ out, int n_dst) {
    const int lane = threadIdx.x & 63, wid = threadIdx.x >> 6;
    const int row = blockIdx.x * 4 + wid;
    if (row >= n_dst) return;

    const int n0 = cnt0[row];
    f4v a = segsum(recs, beg0[row], n0, Y0, lane);
    a *= rsqrtf((float)(n0 < 1 ? 1 : n0));
    if (beg1 != nullptr) {
        const int n1 = cnt1[row];
        f4v a1 = segsum(recs, beg1[row], n1, Y1, lane);
        a += a1 * rsqrtf((float)(n1 < 1 ? 1 : n1));
    }

    float s1 = a[0] + a[1] + a[2] + a[3];
    float s2 = a[0]*a[0] + a[1]*a[1] + a[2]*a[2] + a[3]*a[3];
    #pragma unroll
    for (int off = 1; off < 64; off <<= 1) {
        s1 += __shfl_xor(s1, off);
        s2 += __shfl_xor(s2, off);
    }
    const float mu = s1 * (1.f / 256.f);
    float var = s2 * (1.f / 256.f) - mu * mu;
    var = fmaxf(var, 0.f);
    const float rs = rsqrtf(var + 1e-5f);

    const f4v g  = reinterpret_cast<const f4v*>(gamma)[lane];
    const f4v be = reinterpret_cast<const f4v*>(beta)[lane];
    const f4v bb = reinterpret_cast<const f4v*>(bias)[lane];
    f4v o;
    #pragma unroll
    for (int j = 0; j < 4; ++j) {
        float v = (a[j] - mu) * rs * g[j] + be[j] + bb[j];
        o[j] = fmaxf(v, 0.f);
    }
    reinterpret_cast<f4v*>(out + (size_t)row * DDIM)[lane] = o;
}

extern "C" void kernel_launch(void* const* d_in, const int* in_sizes, int n_in,
                              void* d_out, int out_size, void* d_ws, size_t ws_size,
                              hipStream_t stream) {
    const float* x_cell     = (const float*)d_in[0];
    const float* x_gene     = (const float*)d_in[1];
    const float* W_cg       = (const float*)d_in[2];
    const float* W_gc       = (const float*)d_in[3];
    const float* W_gg       = (const float*)d_in[4];
    const float* gamma_cell = (const float*)d_in[5];
    const float* beta_cell  = (const float*)d_in[6];
    const float* gamma_gene = (const float*)d_in[7];
    const float* beta_gene  = (const float*)d_in[8];
    const float* b_cell     = (const float*)d_in[9];
    const float* b_gene     = (const float*)d_in[10];
    const int* src_cg = (const int*)d_in[11];
    const int* dst_cg = (const int*)d_in[12];
    const int* src_gc = (const int*)d_in[13];
    const int* dst_gc = (const int*)d_in[14];
    const int* src_gg = (const int*)d_in[15];
    const int* dst_gg = (const int*)d_in[16];

    const int N = in_sizes[0] / DDIM;        // 50000
    const int E = in_sizes[11];              // 800000
    const int ncb = (N + 511) >> 9;          // 98 used coarse bins

    // ---- workspace layout (~54 MB) ----
    char* wsb = (char*)d_ws;
    size_t off = 0;
    __hip_bfloat16* Y_gc = (__hip_bfloat16*)(wsb + off); off += (size_t)N * DDIM * 2;             // 25.6 MB
    unsigned* recs32 = (unsigned*)(wsb + off);           off += (size_t)3 * NCPAD * CCAP * 4;     // 14.2 MB
    unsigned short* recs16 = (unsigned short*)(wsb + off); off += (size_t)3 * NCPAD * CCAP * 2;   // 7.1 MB
    int* row_beg = (int*)(wsb + off);                    off += (size_t)3 * N * 4;                // 600 KB
    int* row_cnt = (int*)(wsb + off);                    off += (size_t)3 * N * 4;                // 600 KB
    const size_t zeroOff = off;
    int* cs_shard = (int*)(wsb + off);                   off += (size_t)NSHARD * 3 * N * 4;       // 4.8 MB
    int* gcur     = (int*)(wsb + off);                   off += (size_t)3 * NCPAD * 4;            // 1.5 KB
    const size_t zeroBytes = off - zeroOff;
    __hip_bfloat16* Wt_gc = (__hip_bfloat16*)(wsb + off); off += (size_t)DDIM * DDIM * 2;
    __hip_bfloat16* Wt_cg = (__hip_bfloat16*)(wsb + off); off += (size_t)DDIM * DDIM * 2;
    __hip_bfloat16* Wt_gg = (__hip_bfloat16*)(wsb + off);

    int* beg_gc = row_beg, *beg_cg = row_beg + N, *beg_gg = row_beg + 2 * N;
    int* cnt_gc = row_cnt, *cnt_cg = row_cnt + N, *cnt_gg = row_cnt + 2 * N;

    // Y_cg, Y_gg live in the d_out cell-half; consumed by the gene gather before
    // the cell gather overwrites that region with the final cell output.
    float* out_cell = (float*)d_out;
    float* out_gene = out_cell + (size_t)N * DDIM;
    __hip_bfloat16* Y_cg = (__hip_bfloat16*)d_out;
    __hip_bfloat16* Y_gg = Y_cg + (size_t)N * DDIM;

    const int binBlocks  = (E + T1 - 1) / T1;
    const int gemmBlocks = (N + 127) / 128;
    const int gatherBlocks = (N + 3) / 4;

    transpose3_k<<<dim3(DDIM, 3), DDIM, 0, stream>>>(W_gc, W_cg, W_gg, Wt_gc, Wt_cg, Wt_gg);
    hipMemsetAsync(wsb + zeroOff, 0, zeroBytes, stream);

    // relations: 0=gc, 1=cg, 2=gg
    bin1_k<<<dim3(binBlocks, 3), 256, 0, stream>>>(src_gc, dst_gc, src_cg, dst_cg,
                                                   src_gg, dst_gg, cs_shard, gcur, recs32, N, E);

    // gemm2 + gemm1 + sort, one dispatch (GEMM blocks first; sort hides in their shadow)
    mid_k<<<2 * gemmBlocks + 3 * ncb, 256, 0, stream>>>(
        recs32, recs16, gcur, row_beg, row_cnt, x_gene, x_cell,
        Wt_gc, Wt_gg, Wt_cg, cs_shard, Y_gc, Y_gg, Y_cg, N, ncb, gemmBlocks);

    // gene: cg + gg fused gather + LN
    gather_ln_k<<<gatherBlocks, 256, 0, stream>>>(recs16, beg_cg, cnt_cg, Y_cg,
                                                  beg_gg, cnt_gg, Y_gg,
                                                  gamma_gene, beta_gene, b_gene, out_gene, N);
    // cell: gc gather + LN (overwrites Y_cg/Y_gg region)
    gather_ln_k<<<gatherBlocks, 256, 0, stream>>>(recs16, beg_gc, cnt_gc, Y_gc,
                                                  nullptr, nullptr, nullptr,
                                                  gamma_cell, beta_cell, b_cell, out_cell, N);
}